// Round 2
// baseline (3191.385 us; speedup 1.0000x reference)
//
#include <hip/hip_runtime.h>
#include <hip/hip_bf16.h>

// ---------------- constants ----------------
#define D_      256
#define NH_     8
#define HD_     32
#define NP_     4
#define NL_     3
#define RTOK    8
#define LQ_     5384
#define SUMHW_  5376
#define B_      2
#define FH_     128
#define HID_    1024
#define EPS_    1e-6f

// workspace offsets (in floats)
#define OFF_S2  0
#define OFF_QB  2756608
#define OFF_VB  5513216
#define OFF_OB  8265728
#define OFF_AW  10333184
#define OFF_CA  5513216
#define OFF_CB  13901824
// total = 22,290,432 floats = 89.2 MB

// ---------------- helpers ----------------
__device__ __forceinline__ float blk_sum(float v, float* scr) {
    #pragma unroll
    for (int o = 32; o > 0; o >>= 1) v += __shfl_down(v, o, 64);
    int w = threadIdx.x >> 6;
    if ((threadIdx.x & 63) == 0) scr[w] = v;
    __syncthreads();
    float s = scr[0] + scr[1] + scr[2] + scr[3];
    __syncthreads();
    return s;
}

// ---------------- LN(src) + query ----------------
__global__ __launch_bounds__(256)
void k_ln_src(const float* __restrict__ src, const float* __restrict__ pos,
              const float* __restrict__ w1, float* __restrict__ S2, float* __restrict__ QB) {
    size_t row = blockIdx.x;
    int c = threadIdx.x;
    __shared__ float scr[4];
    float v = src[row * D_ + c];
    float mean = blk_sum(v, scr) * (1.0f / D_);
    float d = v - mean;
    float var = blk_sum(d * d, scr) * (1.0f / D_);
    float y = d * rsqrtf(var + EPS_) * w1[c];
    S2[row * D_ + c] = y;
    QB[row * D_ + c] = y + pos[row * D_ + c];
}

// ---------------- generic C[M,N] = A[M,256] @ W[N,256]^T + bias ----------------
template<int TM>
__global__ __launch_bounds__(256)
void k_gemm_nt(const float* __restrict__ A, const float* __restrict__ W,
               const float* __restrict__ bias, float* __restrict__ C, int M, int N) {
    __shared__ float a_lds[TM][D_];
    int m0 = blockIdx.x * TM;
    for (int idx = threadIdx.x; idx < TM * D_; idx += 256) {
        int r = idx >> 8, k = idx & 255;
        a_lds[r][k] = (m0 + r < M) ? A[(size_t)(m0 + r) * D_ + k] : 0.f;
    }
    __syncthreads();
    int n = threadIdx.x;
    if (n >= N) return;
    float acc[TM];
    #pragma unroll
    for (int r = 0; r < TM; ++r) acc[r] = 0.f;
    const float* wr = W + (size_t)n * D_;
    for (int k = 0; k < D_; ++k) {
        float w = wr[k];
        #pragma unroll
        for (int r = 0; r < TM; ++r) acc[r] += a_lds[r][k] * w;
    }
    float bb = bias ? bias[n] : 0.f;
    #pragma unroll
    for (int r = 0; r < TM; ++r)
        if (m0 + r < M) C[(size_t)(m0 + r) * N + n] = acc[r] + bb;
}

// ---------------- softmax over 12 ----------------
__global__ __launch_bounds__(256)
void k_softmax12(float* __restrict__ AW, int total) {
    int t = blockIdx.x * 256 + threadIdx.x;
    if (t >= total) return;
    float* p = AW + (size_t)t * 12;
    float m = p[0];
    #pragma unroll
    for (int i = 1; i < 12; ++i) m = fmaxf(m, p[i]);
    float s = 0.f;
    float e[12];
    #pragma unroll
    for (int i = 0; i < 12; ++i) { e[i] = __expf(p[i] - m); s += e[i]; }
    float inv = 1.f / s;
    #pragma unroll
    for (int i = 0; i < 12; ++i) p[i] = e[i] * inv;
}

// ---------------- deformable sampling ----------------
__global__ __launch_bounds__(256)
void k_sample(const float* __restrict__ VB, const float* __restrict__ OB,
              const float* __restrict__ AW, const float* __restrict__ refp,
              float* __restrict__ AT) {
    int bq = blockIdx.x;            // b*LQ + q
    int b  = bq / LQ_;
    int h  = threadIdx.x >> 5;
    int dd = threadIdx.x & 31;
    const float* off = OB + (size_t)bq * 192;
    const float* aw  = AW + (size_t)bq * 96;
    const float* rp  = refp + (size_t)bq * (NL_ * 2);
    const int HS[3] = {64, 32, 16};
    const int ST[3] = {0, 4096, 5120};
    float acc = 0.f;
    #pragma unroll
    for (int l = 0; l < NL_; ++l) {
        float rx = rp[l * 2 + 0], ry = rp[l * 2 + 1];
        int Wl = HS[l], Hl = HS[l];
        float fWl = (float)Wl, fHl = (float)Hl;
        const float* vbase = VB + ((size_t)b * SUMHW_ + ST[l]) * D_ + h * 32 + dd;
        #pragma unroll
        for (int p = 0; p < NP_; ++p) {
            int oi = ((h * NL_ + l) * NP_ + p) * 2;
            float locx = rx + off[oi]     / fWl;
            float locy = ry + off[oi + 1] / fHl;
            float x = locx * fWl - 0.5f;
            float y = locy * fHl - 0.5f;
            float x0f = floorf(x), y0f = floorf(y);
            float fx = x - x0f, fy = y - y0f;
            int x0 = (int)x0f, y0 = (int)y0f;
            float a = aw[(h * NL_ + l) * NP_ + p];
            float g = 0.f;
            if (x0 >= 0     && x0 < Wl     && y0 >= 0     && y0 < Hl)
                g += (1.f - fx) * (1.f - fy) * vbase[(size_t)(y0 * Wl + x0) * D_];
            if (x0 + 1 >= 0 && x0 + 1 < Wl && y0 >= 0     && y0 < Hl)
                g += fx * (1.f - fy) * vbase[(size_t)(y0 * Wl + x0 + 1) * D_];
            if (x0 >= 0     && x0 < Wl     && y0 + 1 >= 0 && y0 + 1 < Hl)
                g += (1.f - fx) * fy * vbase[(size_t)((y0 + 1) * Wl + x0) * D_];
            if (x0 + 1 >= 0 && x0 + 1 < Wl && y0 + 1 >= 0 && y0 + 1 < Hl)
                g += fx * fy * vbase[(size_t)((y0 + 1) * Wl + x0 + 1) * D_];
            acc += a * g;
        }
    }
    AT[(size_t)bq * D_ + threadIdx.x] = acc;
}

// ---------------- build f = feat (+optional LN) + bilinear-upsampled prev ----------------
__global__ __launch_bounds__(256)
void k_build_f(const float* __restrict__ feat, long long feat_bstride, int do_ln,
               const float* __restrict__ w1,
               const float* __restrict__ prev, long long prev_bstride, int PH, int PW,
               float* __restrict__ out, int OH, int OW) {
    int idx = blockIdx.x;
    int x = idx % OW;
    int y = (idx / OW) % OH;
    int b = idx / (OW * OH);
    int c = threadIdx.x;
    __shared__ float scr[4];
    float fv = feat[(size_t)b * feat_bstride + (size_t)(y * OW + x) * D_ + c];
    if (do_ln) {
        float mean = blk_sum(fv, scr) * (1.0f / D_);
        float d = fv - mean;
        float var = blk_sum(d * d, scr) * (1.0f / D_);
        fv = d * rsqrtf(var + EPS_) * w1[c];
    }
    float sy = fmaxf((y + 0.5f) * ((float)PH / OH) - 0.5f, 0.f);
    int y0 = min((int)floorf(sy), PH - 1);
    int y1 = min(y0 + 1, PH - 1);
    float ty = sy - (float)y0;
    float sx = fmaxf((x + 0.5f) * ((float)PW / OW) - 0.5f, 0.f);
    int x0 = min((int)floorf(sx), PW - 1);
    int x1 = min(x0 + 1, PW - 1);
    float tx = sx - (float)x0;
    const float* pb = prev + (size_t)b * prev_bstride;
    float v00 = pb[(size_t)(y0 * PW + x0) * D_ + c];
    float v01 = pb[(size_t)(y0 * PW + x1) * D_ + c];
    float v10 = pb[(size_t)(y1 * PW + x0) * D_ + c];
    float v11 = pb[(size_t)(y1 * PW + x1) * D_ + c];
    float top = v00 * (1.f - tx) + v01 * tx;
    float bot = v10 * (1.f - tx) + v11 * tx;
    out[(size_t)idx * D_ + c] = fv + (top * (1.f - ty) + bot * ty);
}

// ---------------- direct 3x3 conv, SAME, 256->256, 4 pixels/block ----------------
__global__ __launch_bounds__(256)
void k_conv3x3(const float* __restrict__ in, const float* __restrict__ w,
               const float* __restrict__ bias, float* __restrict__ out, int H, int W) {
    int nxb = W >> 2;
    int bid = blockIdx.x;
    int x0 = (bid % nxb) << 2;
    int y  = (bid / nxb) % H;
    int b  = bid / (nxb * H);
    __shared__ float tile[3 * 6 * D_];   // [ky][cx=x0-1..x0+4][k]
    const float* ib = in + (size_t)b * H * W * D_;
    for (int t = threadIdx.x; t < 3 * 6 * D_; t += 256) {
        int k  = t & 255;
        int cx = (t >> 8) % 6;
        int ky = t / (6 * D_);
        int yy = y + ky - 1;
        int xx = x0 + cx - 1;
        float v = 0.f;
        if (yy >= 0 && yy < H && xx >= 0 && xx < W)
            v = ib[(size_t)(yy * W + xx) * D_ + k];
        tile[t] = v;
    }
    __syncthreads();
    int co = threadIdx.x;
    float a0 = bias[co], a1 = a0, a2 = a0, a3 = a0;
    #pragma unroll
    for (int ky = 0; ky < 3; ++ky) {
        #pragma unroll
        for (int kx = 0; kx < 3; ++kx) {
            const float* wp = w + (size_t)(ky * 3 + kx) * D_ * D_ + co;
            const float* tp = tile + (ky * 6 + kx) * D_;
            for (int k = 0; k < D_; ++k) {
                float wv = wp[(size_t)k * D_];
                a0 += tp[k]           * wv;
                a1 += tp[k + D_]      * wv;
                a2 += tp[k + 2 * D_]  * wv;
                a3 += tp[k + 3 * D_]  * wv;
            }
        }
    }
    size_t ob = ((size_t)b * H * W + (size_t)y * W + x0) * D_ + co;
    out[ob]          = a0;
    out[ob + D_]     = a1;
    out[ob + 2 * D_] = a2;
    out[ob + 3 * D_] = a3;
}

// ---------------- fused residual + LN + star-MLP, f32 store ----------------
template<int RPB>
__global__ __launch_bounds__(256)
void k_mlp(const float* __restrict__ a, const float* __restrict__ bsrc,
           const float* __restrict__ n2, const float* __restrict__ fc1,
           const float* __restrict__ fc2, const float* __restrict__ ssp,
           const float* __restrict__ sbp, float* __restrict__ out) {
    __shared__ float x[RPB][D_];
    __shared__ float xn[RPB][D_];
    __shared__ float h[RPB][HID_];
    __shared__ float scr[4];
    int r0 = blockIdx.x * RPB;
    int tid = threadIdx.x;
    float ss = ssp[0], sb = sbp[0];
    #pragma unroll
    for (int r = 0; r < RPB; ++r) {
        size_t o = (size_t)(r0 + r) * D_ + tid;
        x[r][tid] = a[o] + bsrc[o];
    }
    for (int r = 0; r < RPB; ++r) {
        float v = x[r][tid];
        float mean = blk_sum(v, scr) * (1.0f / D_);
        float d = v - mean;
        float var = blk_sum(d * d, scr) * (1.0f / D_);
        xn[r][tid] = d * rsqrtf(var + EPS_) * n2[tid];
    }
    __syncthreads();
    // fc1 + relu + star
    #pragma unroll
    for (int jj = 0; jj < HID_ / 256; ++jj) {
        int j = tid + (jj << 8);
        const float* wr = fc1 + (size_t)j * D_;
        float acc[RPB];
        #pragma unroll
        for (int r = 0; r < RPB; ++r) acc[r] = 0.f;
        for (int k = 0; k < D_; ++k) {
            float w = wr[k];
            #pragma unroll
            for (int r = 0; r < RPB; ++r) acc[r] += xn[r][k] * w;
        }
        #pragma unroll
        for (int r = 0; r < RPB; ++r) {
            float hv = fmaxf(acc[r], 0.f);
            h[r][j] = ss * hv * hv + sb;
        }
    }
    __syncthreads();
    // fc2 + residual
    {
        const float* wr = fc2 + (size_t)tid * HID_;
        float acc[RPB];
        #pragma unroll
        for (int r = 0; r < RPB; ++r) acc[r] = 0.f;
        for (int k = 0; k < HID_; ++k) {
            float w = wr[k];
            #pragma unroll
            for (int r = 0; r < RPB; ++r) acc[r] += h[r][k] * w;
        }
        #pragma unroll
        for (int r = 0; r < RPB; ++r)
            out[(size_t)(r0 + r) * D_ + tid] = x[r][tid] + acc[r];
    }
}

// ---------------- launch ----------------
extern "C" void kernel_launch(void* const* d_in, const int* in_sizes, int n_in,
                              void* d_out, int out_size, void* d_ws, size_t ws_size,
                              hipStream_t stream) {
    const float* src   = (const float*)d_in[0];
    const float* pos   = (const float*)d_in[1];
    const float* fpn   = (const float*)d_in[2];
    const float* refp  = (const float*)d_in[3];
    const float* n1w   = (const float*)d_in[5];
    const float* n2w   = (const float*)d_in[6];
    const float* Wv    = (const float*)d_in[7];
    const float* bv    = (const float*)d_in[8];
    const float* Woff  = (const float*)d_in[9];
    const float* boff  = (const float*)d_in[10];
    const float* Wattn = (const float*)d_in[11];
    const float* battn = (const float*)d_in[12];
    const float* Wout  = (const float*)d_in[13];
    const float* bout  = (const float*)d_in[14];
    const float* convw = (const float*)d_in[15];
    const float* convb = (const float*)d_in[16];
    const float* fc1   = (const float*)d_in[17];
    const float* fc2   = (const float*)d_in[18];
    const float* ssp   = (const float*)d_in[19];
    const float* sbp   = (const float*)d_in[20];

    float* ws = (float*)d_ws;
    float* S2 = ws + OFF_S2;
    float* QB = ws + OFF_QB;
    float* VB = ws + OFF_VB;
    float* OB = ws + OFF_OB;
    float* AW = ws + OFF_AW;
    float* CA = ws + OFF_CA;
    float* CB = ws + OFF_CB;
    float* out = (float*)d_out;

    // 1. LN(src) -> S2 ; query -> QB
    k_ln_src<<<B_ * LQ_, 256, 0, stream>>>(src, pos, n1w, S2, QB);

    // 2. value = S2[:, R:] @ Wv^T + bv  (per batch: contiguous row slice)
    for (int b = 0; b < B_; ++b)
        k_gemm_nt<8><<<SUMHW_ / 8, 256, 0, stream>>>(
            S2 + ((size_t)b * LQ_ + RTOK) * D_, Wv, bv,
            VB + (size_t)b * SUMHW_ * D_, SUMHW_, D_);

    // 3. offsets / attention logits
    k_gemm_nt<8><<<(B_ * LQ_) / 8, 256, 0, stream>>>(QB, Woff, boff, OB, B_ * LQ_, 192);
    k_gemm_nt<8><<<(B_ * LQ_) / 8, 256, 0, stream>>>(QB, Wattn, battn, AW, B_ * LQ_, 96);
    k_softmax12<<<(B_ * LQ_ * NH_ + 255) / 256, 256, 0, stream>>>(AW, B_ * LQ_ * NH_);

    // 4. deformable sampling -> AT (reuse QB)
    k_sample<<<B_ * LQ_, 256, 0, stream>>>(VB, OB, AW, refp, QB);

    // 5. src2 = AT @ Wout^T + bout -> S2 (overwrite)
    k_gemm_nt<8><<<(B_ * LQ_) / 8, 256, 0, stream>>>(QB, Wout, bout, S2, B_ * LQ_, 256);

    // 6. FPN fusion chain
    // stage 0: f = feats32 + up(feats16) ; conv0
    k_build_f<<<B_ * 32 * 32, 256, 0, stream>>>(
        S2 + (size_t)(RTOK + 4096) * D_, (long long)LQ_ * D_, 0, n1w,
        S2 + (size_t)(RTOK + 5120) * D_, (long long)LQ_ * D_, 16, 16,
        CA, 32, 32);
    k_conv3x3<<<B_ * 32 * 8, 256, 0, stream>>>(CA, convw, convb, CB, 32, 32);
    // stage 1: f = feats64 + up(out32) ; conv1
    k_build_f<<<B_ * 64 * 64, 256, 0, stream>>>(
        S2 + (size_t)RTOK * D_, (long long)LQ_ * D_, 0, n1w,
        CB, (long long)32 * 32 * D_, 32, 32,
        CA, 64, 64);
    k_conv3x3<<<B_ * 64 * 16, 256, 0, stream>>>(
        CA, convw + (size_t)1 * 9 * D_ * D_, convb + D_, CB, 64, 64);
    // stage 2: f = LN(fpn) + up(out64) ; conv2
    k_build_f<<<B_ * 128 * 128, 256, 0, stream>>>(
        fpn, (long long)FH_ * FH_ * D_, 1, n1w,
        CB, (long long)64 * 64 * D_, 64, 64,
        CA, 128, 128);
    k_conv3x3<<<B_ * 128 * 32, 256, 0, stream>>>(
        CA, convw + (size_t)2 * 9 * D_ * D_, convb + 2 * D_, CB, 128, 128);

    // 7. fused residual + LN + MLP epilogues (f32 store)
    k_mlp<8><<<(B_ * LQ_) / 8, 256, 0, stream>>>(src, S2, n2w, fc1, fc2, ssp, sbp, out);
    k_mlp<8><<<(B_ * FH_ * FH_) / 8, 256, 0, stream>>>(fpn, CB, n2w, fc1, fc2, ssp, sbp,
                                                       out + (size_t)B_ * LQ_ * D_);
}

// Round 3
// 1633.615 us; speedup vs baseline: 1.9536x; 1.9536x over previous
//
#include <hip/hip_runtime.h>
#include <hip/hip_bf16.h>

// ---------------- constants ----------------
#define D_      256
#define NH_     8
#define HD_     32
#define NP_     4
#define NL_     3
#define RTOK    8
#define LQ_     5384
#define SUMHW_  5376
#define B_      2
#define FH_     128
#define HID_    1024
#define EPS_    1e-6f

// workspace offsets (in floats)
#define OFF_S2  0
#define OFF_QB  2756608
#define OFF_VB  5513216
#define OFF_OB  8265728
#define OFF_AW  10333184
#define OFF_CA  5513216
#define OFF_CB  13901824
// bf16 weight caches (appended)
#define OFF_W1B 22290432   // 262144 shorts = 131072 floats
#define OFF_W2B 22421504   // 262144 shorts
#define OFF_CWB 22552576   // 1769472 shorts = 884736 floats
// total = 23,437,312 floats = 93.7 MB

typedef __attribute__((ext_vector_type(4))) float f32x4;
typedef __attribute__((ext_vector_type(8))) short short8;
typedef __attribute__((ext_vector_type(4))) unsigned short ushort4_;

__device__ __forceinline__ unsigned short f2bf(float f) {
    unsigned u = __float_as_uint(f);
    unsigned r = u + 0x7fff + ((u >> 16) & 1);   // round-to-nearest-even
    return (unsigned short)(r >> 16);
}

// ---------------- helpers ----------------
__device__ __forceinline__ float blk_sum(float v, float* scr) {
    #pragma unroll
    for (int o = 32; o > 0; o >>= 1) v += __shfl_down(v, o, 64);
    int w = threadIdx.x >> 6;
    if ((threadIdx.x & 63) == 0) scr[w] = v;
    __syncthreads();
    float s = scr[0] + scr[1] + scr[2] + scr[3];
    __syncthreads();
    return s;
}

// ---------------- weight prep: f32 -> bf16 ----------------
__global__ __launch_bounds__(256)
void k_cvt_bf16(const float* __restrict__ src, unsigned short* __restrict__ dst, int n) {
    int i = blockIdx.x * 256 + threadIdx.x;
    if (i < n) dst[i] = f2bf(src[i]);
}

// convw [27][256ci][256co] -> dst [27][256co][256ci] bf16
__global__ __launch_bounds__(256)
void k_conv_w_prep(const float* __restrict__ convw, unsigned short* __restrict__ dst) {
    int i = blockIdx.x * 256 + threadIdx.x;   // total 27*65536
    int ci = i & 255;
    int co = (i >> 8) & 255;
    int kk = i >> 16;
    dst[(size_t)kk * 65536 + co * 256 + ci] = f2bf(convw[(size_t)kk * 65536 + ci * 256 + co]);
}

// ---------------- LN(src) + query ----------------
__global__ __launch_bounds__(256)
void k_ln_src(const float* __restrict__ src, const float* __restrict__ pos,
              const float* __restrict__ w1, float* __restrict__ S2, float* __restrict__ QB) {
    size_t row = blockIdx.x;
    int c = threadIdx.x;
    __shared__ float scr[4];
    float v = src[row * D_ + c];
    float mean = blk_sum(v, scr) * (1.0f / D_);
    float d = v - mean;
    float var = blk_sum(d * d, scr) * (1.0f / D_);
    float y = d * rsqrtf(var + EPS_) * w1[c];
    S2[row * D_ + c] = y;
    QB[row * D_ + c] = y + pos[row * D_ + c];
}

// ---------------- generic C[M,N] = A[M,256] @ W[N,256]^T + bias ----------------
template<int TM>
__global__ __launch_bounds__(256)
void k_gemm_nt(const float* __restrict__ A, const float* __restrict__ W,
               const float* __restrict__ bias, float* __restrict__ C, int M, int N) {
    __shared__ float a_lds[TM][D_];
    int m0 = blockIdx.x * TM;
    for (int idx = threadIdx.x; idx < TM * D_; idx += 256) {
        int r = idx >> 8, k = idx & 255;
        a_lds[r][k] = (m0 + r < M) ? A[(size_t)(m0 + r) * D_ + k] : 0.f;
    }
    __syncthreads();
    int n = threadIdx.x;
    if (n >= N) return;
    float acc[TM];
    #pragma unroll
    for (int r = 0; r < TM; ++r) acc[r] = 0.f;
    const float* wr = W + (size_t)n * D_;
    for (int k = 0; k < D_; ++k) {
        float w = wr[k];
        #pragma unroll
        for (int r = 0; r < TM; ++r) acc[r] += a_lds[r][k] * w;
    }
    float bb = bias ? bias[n] : 0.f;
    #pragma unroll
    for (int r = 0; r < TM; ++r)
        if (m0 + r < M) C[(size_t)(m0 + r) * N + n] = acc[r] + bb;
}

// ---------------- softmax over 12 ----------------
__global__ __launch_bounds__(256)
void k_softmax12(float* __restrict__ AW, int total) {
    int t = blockIdx.x * 256 + threadIdx.x;
    if (t >= total) return;
    float* p = AW + (size_t)t * 12;
    float m = p[0];
    #pragma unroll
    for (int i = 1; i < 12; ++i) m = fmaxf(m, p[i]);
    float s = 0.f;
    float e[12];
    #pragma unroll
    for (int i = 0; i < 12; ++i) { e[i] = __expf(p[i] - m); s += e[i]; }
    float inv = 1.f / s;
    #pragma unroll
    for (int i = 0; i < 12; ++i) p[i] = e[i] * inv;
}

// ---------------- deformable sampling ----------------
__global__ __launch_bounds__(256)
void k_sample(const float* __restrict__ VB, const float* __restrict__ OB,
              const float* __restrict__ AW, const float* __restrict__ refp,
              float* __restrict__ AT) {
    int bq = blockIdx.x;            // b*LQ + q
    int b  = bq / LQ_;
    int h  = threadIdx.x >> 5;
    int dd = threadIdx.x & 31;
    const float* off = OB + (size_t)bq * 192;
    const float* aw  = AW + (size_t)bq * 96;
    const float* rp  = refp + (size_t)bq * (NL_ * 2);
    const int HS[3] = {64, 32, 16};
    const int ST[3] = {0, 4096, 5120};
    float acc = 0.f;
    #pragma unroll
    for (int l = 0; l < NL_; ++l) {
        float rx = rp[l * 2 + 0], ry = rp[l * 2 + 1];
        int Wl = HS[l], Hl = HS[l];
        float fWl = (float)Wl, fHl = (float)Hl;
        const float* vbase = VB + ((size_t)b * SUMHW_ + ST[l]) * D_ + h * 32 + dd;
        #pragma unroll
        for (int p = 0; p < NP_; ++p) {
            int oi = ((h * NL_ + l) * NP_ + p) * 2;
            float locx = rx + off[oi]     / fWl;
            float locy = ry + off[oi + 1] / fHl;
            float x = locx * fWl - 0.5f;
            float y = locy * fHl - 0.5f;
            float x0f = floorf(x), y0f = floorf(y);
            float fx = x - x0f, fy = y - y0f;
            int x0 = (int)x0f, y0 = (int)y0f;
            float a = aw[(h * NL_ + l) * NP_ + p];
            float g = 0.f;
            if (x0 >= 0     && x0 < Wl     && y0 >= 0     && y0 < Hl)
                g += (1.f - fx) * (1.f - fy) * vbase[(size_t)(y0 * Wl + x0) * D_];
            if (x0 + 1 >= 0 && x0 + 1 < Wl && y0 >= 0     && y0 < Hl)
                g += fx * (1.f - fy) * vbase[(size_t)(y0 * Wl + x0 + 1) * D_];
            if (x0 >= 0     && x0 < Wl     && y0 + 1 >= 0 && y0 + 1 < Hl)
                g += (1.f - fx) * fy * vbase[(size_t)((y0 + 1) * Wl + x0) * D_];
            if (x0 + 1 >= 0 && x0 + 1 < Wl && y0 + 1 >= 0 && y0 + 1 < Hl)
                g += fx * fy * vbase[(size_t)((y0 + 1) * Wl + x0 + 1) * D_];
            acc += a * g;
        }
    }
    AT[(size_t)bq * D_ + threadIdx.x] = acc;
}

// ---------------- build f = feat (+optional LN) + bilinear-upsampled prev ----------------
__global__ __launch_bounds__(256)
void k_build_f(const float* __restrict__ feat, long long feat_bstride, int do_ln,
               const float* __restrict__ w1,
               const float* __restrict__ prev, long long prev_bstride, int PH, int PW,
               float* __restrict__ out, int OH, int OW) {
    int idx = blockIdx.x;
    int x = idx % OW;
    int y = (idx / OW) % OH;
    int b = idx / (OW * OH);
    int c = threadIdx.x;
    __shared__ float scr[4];
    float fv = feat[(size_t)b * feat_bstride + (size_t)(y * OW + x) * D_ + c];
    if (do_ln) {
        float mean = blk_sum(fv, scr) * (1.0f / D_);
        float d = fv - mean;
        float var = blk_sum(d * d, scr) * (1.0f / D_);
        fv = d * rsqrtf(var + EPS_) * w1[c];
    }
    float sy = fmaxf((y + 0.5f) * ((float)PH / OH) - 0.5f, 0.f);
    int y0 = min((int)floorf(sy), PH - 1);
    int y1 = min(y0 + 1, PH - 1);
    float ty = sy - (float)y0;
    float sx = fmaxf((x + 0.5f) * ((float)PW / OW) - 0.5f, 0.f);
    int x0 = min((int)floorf(sx), PW - 1);
    int x1 = min(x0 + 1, PW - 1);
    float tx = sx - (float)x0;
    const float* pb = prev + (size_t)b * prev_bstride;
    float v00 = pb[(size_t)(y0 * PW + x0) * D_ + c];
    float v01 = pb[(size_t)(y0 * PW + x1) * D_ + c];
    float v10 = pb[(size_t)(y1 * PW + x0) * D_ + c];
    float v11 = pb[(size_t)(y1 * PW + x1) * D_ + c];
    float top = v00 * (1.f - tx) + v01 * tx;
    float bot = v10 * (1.f - tx) + v11 * tx;
    out[(size_t)idx * D_ + c] = fv + (top * (1.f - ty) + bot * ty);
}

// ---------------- MFMA 3x3 conv: 32 pixels x 256 co per block ----------------
__global__ __launch_bounds__(256)
void k_conv_mfma(const float* __restrict__ in, const unsigned short* __restrict__ wb,
                 const float* __restrict__ bias, float* __restrict__ out, int H, int W) {
    int nxb = W >> 5;
    int bid = blockIdx.x;
    int x0 = (bid % nxb) << 5;
    int y  = (bid / nxb) % H;
    int b  = bid / (nxb * H);
    __shared__ unsigned short tile[3 * 34 * 256];   // [ky][cx 0..33][ci], swizzled by cx
    const float* ib = in + (size_t)b * H * W * 256;
    // stage 3 input rows (bf16, swizzled)
    for (int t = threadIdx.x; t < 6528; t += 256) {   // 102 (ky,cx) rows x 64 float4
        int ci4 = (t & 63) << 2;
        int cxky = t >> 6;
        int cx = cxky % 34;
        int ky = cxky / 34;
        int gy = y + ky - 1;
        int gx = x0 + cx - 1;
        float4 v = make_float4(0.f, 0.f, 0.f, 0.f);
        if (gy >= 0 && gy < H && gx >= 0 && gx < W)
            v = *(const float4*)&ib[((size_t)gy * W + gx) * 256 + ci4];
        ushort4_ p;
        p.x = f2bf(v.x); p.y = f2bf(v.y); p.z = f2bf(v.z); p.w = f2bf(v.w);
        *(ushort4_*)&tile[(ky * 34 + cx) * 256 + (ci4 ^ ((cx & 7) << 3))] = p;
    }
    __syncthreads();
    int l = threadIdx.x & 63;
    int w = threadIdx.x >> 6;
    int rt = w & 1;               // pixel row-tile (16 px)
    int cb = (w >> 1) * 8;        // coltile base (8 tiles of 16 co)
    int kA = (l >> 4) * 8;
    f32x4 acc[8];
    #pragma unroll
    for (int i = 0; i < 8; ++i) acc[i] = (f32x4){0.f, 0.f, 0.f, 0.f};
    #pragma unroll
    for (int ky = 0; ky < 3; ++ky) {
        #pragma unroll
        for (int kx = 0; kx < 3; ++kx) {
            const unsigned short* ws = wb + (size_t)(ky * 3 + kx) * 65536;
            int cx = rt * 16 + (l & 15) + kx;
            const unsigned short* trow = &tile[(ky * 34 + cx) * 256];
            int swz = (cx & 7) << 3;
            #pragma unroll
            for (int ks = 0; ks < 8; ++ks) {
                short8 af = *(const short8*)&trow[(ks * 32 + kA) ^ swz];
                #pragma unroll
                for (int ct = 0; ct < 8; ++ct) {
                    int co = (cb + ct) * 16 + (l & 15);
                    short8 bf = *(const short8*)&ws[(size_t)co * 256 + ks * 32 + kA];
                    acc[ct] = __builtin_amdgcn_mfma_f32_16x16x32_bf16(af, bf, acc[ct], 0, 0, 0);
                }
            }
        }
    }
    // store
    size_t orow = ((size_t)b * H + y) * W;
    #pragma unroll
    for (int q = 0; q < 4; ++q) {
        int px = x0 + rt * 16 + (l >> 4) * 4 + q;
        #pragma unroll
        for (int ct = 0; ct < 8; ++ct) {
            int co = (cb + ct) * 16 + (l & 15);
            out[(orow + px) * 256 + co] = acc[ct][q] + bias[co];
        }
    }
}

// ---------------- fused residual + LN + star-MLP via MFMA ----------------
__global__ __launch_bounds__(256)
void k_mlp_mfma(const float* __restrict__ a, const float* __restrict__ bsrc,
                const float* __restrict__ n2,
                const unsigned short* __restrict__ W1b, const unsigned short* __restrict__ W2b,
                const float* __restrict__ ssp, const float* __restrict__ sbp,
                float* __restrict__ out, int M) {
    __shared__ unsigned short Xn[64 * 256];     // swizzled bf16 LN output
    __shared__ unsigned short Hc[4 * 16 * 128]; // per-wave H chunk, swizzled
    int r0 = blockIdx.x * 64;
    int w = threadIdx.x >> 6;
    int l = threadIdx.x & 63;
    float ss = ssp[0], sb = sbp[0];
    // ---- LN: wave w handles rows 16w..16w+15 (wave-private throughout) ----
    #pragma unroll 4
    for (int i = 0; i < 16; ++i) {
        int r = w * 16 + i;
        int row = r0 + r;
        float4 xa = make_float4(0.f, 0.f, 0.f, 0.f), xb = xa;
        if (row < M) {
            xa = *(const float4*)&a[(size_t)row * 256 + l * 4];
            xb = *(const float4*)&bsrc[(size_t)row * 256 + l * 4];
        }
        float v0 = xa.x + xb.x, v1 = xa.y + xb.y, v2 = xa.z + xb.z, v3 = xa.w + xb.w;
        float s = v0 + v1 + v2 + v3;
        #pragma unroll
        for (int o = 32; o > 0; o >>= 1) s += __shfl_xor(s, o);
        float mean = s * (1.f / 256.f);
        float d0 = v0 - mean, d1 = v1 - mean, d2 = v2 - mean, d3 = v3 - mean;
        float vv = d0 * d0 + d1 * d1 + d2 * d2 + d3 * d3;
        #pragma unroll
        for (int o = 32; o > 0; o >>= 1) vv += __shfl_xor(vv, o);
        float rs = rsqrtf(vv * (1.f / 256.f) + EPS_);
        float4 nw = *(const float4*)&n2[l * 4];
        ushort4_ p;
        p.x = f2bf(d0 * rs * nw.x); p.y = f2bf(d1 * rs * nw.y);
        p.z = f2bf(d2 * rs * nw.z); p.w = f2bf(d3 * rs * nw.w);
        *(ushort4_*)&Xn[r * 256 + ((l * 4) ^ ((i & 7) << 3))] = p;
    }
    // ---- MLP ----
    int rA = 16 * w + (l & 15);
    int swzA = ((l & 15) & 7) << 3;
    int kA = (l >> 4) * 8;
    f32x4 oacc[16];
    #pragma unroll
    for (int i = 0; i < 16; ++i) oacc[i] = (f32x4){0.f, 0.f, 0.f, 0.f};
    for (int nc = 0; nc < 8; ++nc) {
        f32x4 hacc[8];
        #pragma unroll
        for (int i = 0; i < 8; ++i) hacc[i] = (f32x4){0.f, 0.f, 0.f, 0.f};
        #pragma unroll
        for (int ks = 0; ks < 8; ++ks) {
            short8 af = *(const short8*)&Xn[rA * 256 + ((ks * 32 + kA) ^ swzA)];
            #pragma unroll
            for (int ct = 0; ct < 8; ++ct) {
                int n = nc * 128 + ct * 16 + (l & 15);
                short8 bf = *(const short8*)&W1b[(size_t)n * 256 + ks * 32 + kA];
                hacc[ct] = __builtin_amdgcn_mfma_f32_16x16x32_bf16(af, bf, hacc[ct], 0, 0, 0);
            }
        }
        // relu + star -> Hc (wave-private slice)
        #pragma unroll
        for (int ct = 0; ct < 8; ++ct) {
            #pragma unroll
            for (int q = 0; q < 4; ++q) {
                float hv = fmaxf(hacc[ct][q], 0.f);
                hv = ss * hv * hv + sb;
                int rr = (l >> 4) * 4 + q;
                int cc = ct * 16 + (l & 15);
                Hc[w * 2048 + rr * 128 + (cc ^ ((rr & 7) << 3))] = f2bf(hv);
            }
        }
        // fc2 partial accumulation (K = this 128-chunk)
        #pragma unroll
        for (int ks2 = 0; ks2 < 4; ++ks2) {
            short8 af2 = *(const short8*)&Hc[w * 2048 + (l & 15) * 128 + ((ks2 * 32 + kA) ^ swzA)];
            #pragma unroll
            for (int ot = 0; ot < 16; ++ot) {
                int o = ot * 16 + (l & 15);
                short8 bf2 = *(const short8*)&W2b[(size_t)o * 1024 + nc * 128 + ks2 * 32 + kA];
                oacc[ot] = __builtin_amdgcn_mfma_f32_16x16x32_bf16(af2, bf2, oacc[ot], 0, 0, 0);
            }
        }
    }
    // ---- epilogue: out = a + bsrc + fc2 ----
    #pragma unroll
    for (int q = 0; q < 4; ++q) {
        int row = r0 + 16 * w + (l >> 4) * 4 + q;
        if (row < M) {
            #pragma unroll
            for (int ot = 0; ot < 16; ++ot) {
                int col = ot * 16 + (l & 15);
                size_t off = (size_t)row * 256 + col;
                out[off] = a[off] + bsrc[off] + oacc[ot][q];
            }
        }
    }
}

// ---------------- launch ----------------
extern "C" void kernel_launch(void* const* d_in, const int* in_sizes, int n_in,
                              void* d_out, int out_size, void* d_ws, size_t ws_size,
                              hipStream_t stream) {
    const float* src   = (const float*)d_in[0];
    const float* pos   = (const float*)d_in[1];
    const float* fpn   = (const float*)d_in[2];
    const float* refp  = (const float*)d_in[3];
    const float* n1w   = (const float*)d_in[5];
    const float* n2w   = (const float*)d_in[6];
    const float* Wv    = (const float*)d_in[7];
    const float* bv    = (const float*)d_in[8];
    const float* Woff  = (const float*)d_in[9];
    const float* boff  = (const float*)d_in[10];
    const float* Wattn = (const float*)d_in[11];
    const float* battn = (const float*)d_in[12];
    const float* Wout  = (const float*)d_in[13];
    const float* bout  = (const float*)d_in[14];
    const float* convw = (const float*)d_in[15];
    const float* convb = (const float*)d_in[16];
    const float* fc1   = (const float*)d_in[17];
    const float* fc2   = (const float*)d_in[18];
    const float* ssp   = (const float*)d_in[19];
    const float* sbp   = (const float*)d_in[20];

    float* ws = (float*)d_ws;
    float* S2 = ws + OFF_S2;
    float* QB = ws + OFF_QB;
    float* VB = ws + OFF_VB;
    float* OB = ws + OFF_OB;
    float* AW = ws + OFF_AW;
    float* CA = ws + OFF_CA;
    float* CB = ws + OFF_CB;
    unsigned short* W1B = (unsigned short*)(ws + OFF_W1B);
    unsigned short* W2B = (unsigned short*)(ws + OFF_W2B);
    unsigned short* CWB = (unsigned short*)(ws + OFF_CWB);
    float* out = (float*)d_out;

    // 0. weight prep (bf16)
    k_cvt_bf16<<<(262144 + 255) / 256, 256, 0, stream>>>(fc1, W1B, 262144);
    k_cvt_bf16<<<(262144 + 255) / 256, 256, 0, stream>>>(fc2, W2B, 262144);
    k_conv_w_prep<<<(1769472 + 255) / 256, 256, 0, stream>>>(convw, CWB);

    // 1. LN(src) -> S2 ; query -> QB
    k_ln_src<<<B_ * LQ_, 256, 0, stream>>>(src, pos, n1w, S2, QB);

    // 2. value projection
    for (int b = 0; b < B_; ++b)
        k_gemm_nt<8><<<SUMHW_ / 8, 256, 0, stream>>>(
            S2 + ((size_t)b * LQ_ + RTOK) * D_, Wv, bv,
            VB + (size_t)b * SUMHW_ * D_, SUMHW_, D_);

    // 3. offsets / attention logits
    k_gemm_nt<8><<<(B_ * LQ_) / 8, 256, 0, stream>>>(QB, Woff, boff, OB, B_ * LQ_, 192);
    k_gemm_nt<8><<<(B_ * LQ_) / 8, 256, 0, stream>>>(QB, Wattn, battn, AW, B_ * LQ_, 96);
    k_softmax12<<<(B_ * LQ_ * NH_ + 255) / 256, 256, 0, stream>>>(AW, B_ * LQ_ * NH_);

    // 4. deformable sampling -> AT (reuse QB)
    k_sample<<<B_ * LQ_, 256, 0, stream>>>(VB, OB, AW, refp, QB);

    // 5. src2 = AT @ Wout^T + bout -> S2
    k_gemm_nt<8><<<(B_ * LQ_) / 8, 256, 0, stream>>>(QB, Wout, bout, S2, B_ * LQ_, 256);

    // 6. FPN fusion chain (convs via MFMA)
    k_build_f<<<B_ * 32 * 32, 256, 0, stream>>>(
        S2 + (size_t)(RTOK + 4096) * D_, (long long)LQ_ * D_, 0, n1w,
        S2 + (size_t)(RTOK + 5120) * D_, (long long)LQ_ * D_, 16, 16,
        CA, 32, 32);
    k_conv_mfma<<<1 * 32 * B_, 256, 0, stream>>>(CA, CWB, convb, CB, 32, 32);
    k_build_f<<<B_ * 64 * 64, 256, 0, stream>>>(
        S2 + (size_t)RTOK * D_, (long long)LQ_ * D_, 0, n1w,
        CB, (long long)32 * 32 * D_, 32, 32,
        CA, 64, 64);
    k_conv_mfma<<<2 * 64 * B_, 256, 0, stream>>>(CA, CWB + (size_t)9 * 65536, convb + D_, CB, 64, 64);
    k_build_f<<<B_ * 128 * 128, 256, 0, stream>>>(
        fpn, (long long)FH_ * FH_ * D_, 1, n1w,
        CB, (long long)64 * 64 * D_, 64, 64,
        CA, 128, 128);
    k_conv_mfma<<<4 * 128 * B_, 256, 0, stream>>>(CA, CWB + (size_t)18 * 65536, convb + 2 * D_, CB, 128, 128);

    // 7. fused residual + LN + MLP epilogues (MFMA)
    k_mlp_mfma<<<(B_ * LQ_ + 63) / 64, 256, 0, stream>>>(src, S2, n2w, W1B, W2B, ssp, sbp,
                                                         out, B_ * LQ_);
    k_mlp_mfma<<<(B_ * FH_ * FH_) / 64, 256, 0, stream>>>(fpn, CB, n2w, W1B, W2B, ssp, sbp,
                                                          out + (size_t)B_ * LQ_ * D_, B_ * FH_ * FH_);
}

// Round 4
// 1129.092 us; speedup vs baseline: 2.8265x; 1.4468x over previous
//
#include <hip/hip_runtime.h>
#include <hip/hip_bf16.h>

// ---------------- constants ----------------
#define D_      256
#define NH_     8
#define HD_     32
#define NP_     4
#define NL_     3
#define RTOK    8
#define LQ_     5384
#define SUMHW_  5376
#define B_      2
#define FH_     128
#define HID_    1024
#define EPS_    1e-6f

// workspace offsets (in floats)
#define OFF_S2  0
#define OFF_QB  2756608
#define OFF_VB  5513216
#define OFF_OB  8265728
#define OFF_AW  10333184
#define OFF_CA  5513216
#define OFF_CB  13901824
// bf16 weight caches
#define OFF_W1B 22290432   // fc1  1024x256 bf16
#define OFF_W2B 22421504   // fc2  256x1024 bf16
#define OFF_CWB 22552576   // conv 27x256x256 bf16 (transposed)
#define OFF_WVB 23437312   // Wv   256x256 bf16
#define OFF_WOFB 23470080  // Woff 192x256 bf16
#define OFF_WATB 23494656  // Wattn 96->128x256 bf16 (zero-padded)
#define OFF_WOUB 23511040  // Wout 256x256 bf16
// total = 23,543,808 floats = 94.2 MB

typedef __attribute__((ext_vector_type(4))) float f32x4;
typedef __attribute__((ext_vector_type(8))) short short8;
typedef __attribute__((ext_vector_type(4))) unsigned short ushort4_;

__device__ __forceinline__ unsigned short f2bf(float f) {
    unsigned u = __float_as_uint(f);
    unsigned r = u + 0x7fff + ((u >> 16) & 1);   // RNE
    return (unsigned short)(r >> 16);
}

// ---------------- helpers ----------------
__device__ __forceinline__ float blk_sum(float v, float* scr) {
    #pragma unroll
    for (int o = 32; o > 0; o >>= 1) v += __shfl_down(v, o, 64);
    int w = threadIdx.x >> 6;
    if ((threadIdx.x & 63) == 0) scr[w] = v;
    __syncthreads();
    float s = scr[0] + scr[1] + scr[2] + scr[3];
    __syncthreads();
    return s;
}

// ---------------- weight prep: f32 -> bf16 (with zero pad) ----------------
__global__ __launch_bounds__(256)
void k_cvt_pad(const float* __restrict__ src, unsigned short* __restrict__ dst,
               int nreal, int ntot) {
    int i = blockIdx.x * 256 + threadIdx.x;
    if (i < ntot) dst[i] = (i < nreal) ? f2bf(src[i]) : (unsigned short)0;
}

// convw [27][256ci][256co] -> dst [27][256co][256ci] bf16
__global__ __launch_bounds__(256)
void k_conv_w_prep(const float* __restrict__ convw, unsigned short* __restrict__ dst) {
    int i = blockIdx.x * 256 + threadIdx.x;   // total 27*65536
    int ci = i & 255;
    int co = (i >> 8) & 255;
    int kk = i >> 16;
    dst[(size_t)kk * 65536 + co * 256 + ci] = f2bf(convw[(size_t)kk * 65536 + ci * 256 + co]);
}

// ---------------- LN(src) + query ----------------
__global__ __launch_bounds__(256)
void k_ln_src(const float* __restrict__ src, const float* __restrict__ pos,
              const float* __restrict__ w1, float* __restrict__ S2, float* __restrict__ QB) {
    size_t row = blockIdx.x;
    int c = threadIdx.x;
    __shared__ float scr[4];
    float v = src[row * D_ + c];
    float mean = blk_sum(v, scr) * (1.0f / D_);
    float d = v - mean;
    float var = blk_sum(d * d, scr) * (1.0f / D_);
    float y = d * rsqrtf(var + EPS_) * w1[c];
    S2[row * D_ + c] = y;
    QB[row * D_ + c] = y + pos[row * D_ + c];
}

// =====================================================================
// MFMA GEMM: C[M,N] = A[M,256] @ W[N,256]^T + bias
// 64 rows/block; A bf16-swizzled in LDS then register frags;
// weights staged per 64-out chunk into LDS (bf16 swizzled).
// =====================================================================
template<int NCHUNK>
__global__ __launch_bounds__(256)
void k_gemm_mfma(const float* __restrict__ A, long long a_bstride,
                 const unsigned short* __restrict__ Wb,
                 const float* __restrict__ bias, float* __restrict__ C,
                 long long c_bstride, int M, int N) {
    __shared__ unsigned short buf[16384];   // 32KB: A image, then W chunks
    int b = blockIdx.y;
    const float* Ab = A + (size_t)b * a_bstride;
    float* Cb = C + (size_t)b * c_bstride;
    int r0 = blockIdx.x * 64;
    int tid = threadIdx.x;
    int w = tid >> 6, l = tid & 63;

    // ---- stage A (f32 -> bf16, swizzled) ----
    for (int g = tid; g < 2048; g += 256) {
        int r = g >> 5, e8 = g & 31;
        int row = r0 + r;
        float4 v0 = make_float4(0.f,0.f,0.f,0.f), v1 = v0;
        if (row < M) {
            v0 = *(const float4*)&Ab[(size_t)row * 256 + e8 * 8];
            v1 = *(const float4*)&Ab[(size_t)row * 256 + e8 * 8 + 4];
        }
        short8 p;
        p[0]=f2bf(v0.x); p[1]=f2bf(v0.y); p[2]=f2bf(v0.z); p[3]=f2bf(v0.w);
        p[4]=f2bf(v1.x); p[5]=f2bf(v1.y); p[6]=f2bf(v1.z); p[7]=f2bf(v1.w);
        *(short8*)&buf[r * 256 + ((e8 * 8) ^ ((r & 7) << 3))] = p;
    }
    __syncthreads();
    // ---- A frags -> regs ----
    int rA = 16 * w + (l & 15);
    int kA = (l >> 4) * 8;
    int swzA = (rA & 7) << 3;
    short8 af[8];
    #pragma unroll
    for (int ks = 0; ks < 8; ++ks)
        af[ks] = *(const short8*)&buf[rA * 256 + ((kA + ks * 32) ^ swzA)];
    __syncthreads();

    // ---- chunk loop over outputs ----
    for (int nc = 0; nc < NCHUNK; ++nc) {
        // stage W chunk [64 n x 256 k]
        for (int g = tid; g < 2048; g += 256) {
            int n = g >> 5, e8 = g & 31;
            short8 p = *(const short8*)&Wb[(size_t)(nc * 64 + n) * 256 + e8 * 8];
            *(short8*)&buf[n * 256 + ((e8 * 8) ^ ((n & 7) << 3))] = p;
        }
        __syncthreads();
        f32x4 acc[4];
        #pragma unroll
        for (int i = 0; i < 4; ++i) acc[i] = (f32x4){0.f,0.f,0.f,0.f};
        #pragma unroll
        for (int ks = 0; ks < 8; ++ks) {
            #pragma unroll
            for (int ct = 0; ct < 4; ++ct) {
                int n = ct * 16 + (l & 15);
                short8 bf = *(const short8*)&buf[n * 256 + ((kA + ks * 32) ^ ((n & 7) << 3))];
                acc[ct] = __builtin_amdgcn_mfma_f32_16x16x32_bf16(af[ks], bf, acc[ct], 0, 0, 0);
            }
        }
        // store
        #pragma unroll
        for (int ct = 0; ct < 4; ++ct) {
            int n = nc * 64 + ct * 16 + (l & 15);
            if (n < N) {
                float bb = bias ? bias[n] : 0.f;
                #pragma unroll
                for (int q = 0; q < 4; ++q) {
                    int row = r0 + 16 * w + (l >> 4) * 4 + q;
                    if (row < M) Cb[(size_t)row * N + n] = acc[ct][q] + bb;
                }
            }
        }
        __syncthreads();
    }
}

// ---------------- softmax over 12 ----------------
__global__ __launch_bounds__(256)
void k_softmax12(float* __restrict__ AW, int total) {
    int t = blockIdx.x * 256 + threadIdx.x;
    if (t >= total) return;
    float* p = AW + (size_t)t * 12;
    float m = p[0];
    #pragma unroll
    for (int i = 1; i < 12; ++i) m = fmaxf(m, p[i]);
    float s = 0.f;
    float e[12];
    #pragma unroll
    for (int i = 0; i < 12; ++i) { e[i] = __expf(p[i] - m); s += e[i]; }
    float inv = 1.f / s;
    #pragma unroll
    for (int i = 0; i < 12; ++i) p[i] = e[i] * inv;
}

// ---------------- deformable sampling ----------------
__global__ __launch_bounds__(256)
void k_sample(const float* __restrict__ VB, const float* __restrict__ OB,
              const float* __restrict__ AW, const float* __restrict__ refp,
              float* __restrict__ AT) {
    int bq = blockIdx.x;            // b*LQ + q
    int b  = bq / LQ_;
    int h  = threadIdx.x >> 5;
    int dd = threadIdx.x & 31;
    const float* off = OB + (size_t)bq * 192;
    const float* aw  = AW + (size_t)bq * 96;
    const float* rp  = refp + (size_t)bq * (NL_ * 2);
    const int HS[3] = {64, 32, 16};
    const int ST[3] = {0, 4096, 5120};
    float acc = 0.f;
    #pragma unroll
    for (int l = 0; l < NL_; ++l) {
        float rx = rp[l * 2 + 0], ry = rp[l * 2 + 1];
        int Wl = HS[l], Hl = HS[l];
        float fWl = (float)Wl, fHl = (float)Hl;
        const float* vbase = VB + ((size_t)b * SUMHW_ + ST[l]) * D_ + h * 32 + dd;
        #pragma unroll
        for (int p = 0; p < NP_; ++p) {
            int oi = ((h * NL_ + l) * NP_ + p) * 2;
            float locx = rx + off[oi]     / fWl;
            float locy = ry + off[oi + 1] / fHl;
            float x = locx * fWl - 0.5f;
            float y = locy * fHl - 0.5f;
            float x0f = floorf(x), y0f = floorf(y);
            float fx = x - x0f, fy = y - y0f;
            int x0 = (int)x0f, y0 = (int)y0f;
            float a = aw[(h * NL_ + l) * NP_ + p];
            float g = 0.f;
            if (x0 >= 0     && x0 < Wl     && y0 >= 0     && y0 < Hl)
                g += (1.f - fx) * (1.f - fy) * vbase[(size_t)(y0 * Wl + x0) * D_];
            if (x0 + 1 >= 0 && x0 + 1 < Wl && y0 >= 0     && y0 < Hl)
                g += fx * (1.f - fy) * vbase[(size_t)(y0 * Wl + x0 + 1) * D_];
            if (x0 >= 0     && x0 < Wl     && y0 + 1 >= 0 && y0 + 1 < Hl)
                g += (1.f - fx) * fy * vbase[(size_t)((y0 + 1) * Wl + x0) * D_];
            if (x0 + 1 >= 0 && x0 + 1 < Wl && y0 + 1 >= 0 && y0 + 1 < Hl)
                g += fx * fy * vbase[(size_t)((y0 + 1) * Wl + x0 + 1) * D_];
            acc += a * g;
        }
    }
    AT[(size_t)bq * D_ + threadIdx.x] = acc;
}

// ---------------- build f = feat (+optional LN) + bilinear-upsampled prev ----------------
__global__ __launch_bounds__(256)
void k_build_f(const float* __restrict__ feat, long long feat_bstride, int do_ln,
               const float* __restrict__ w1,
               const float* __restrict__ prev, long long prev_bstride, int PH, int PW,
               float* __restrict__ out, int OH, int OW) {
    int idx = blockIdx.x;
    int x = idx % OW;
    int y = (idx / OW) % OH;
    int b = idx / (OW * OH);
    int c = threadIdx.x;
    __shared__ float scr[4];
    float fv = feat[(size_t)b * feat_bstride + (size_t)(y * OW + x) * D_ + c];
    if (do_ln) {
        float mean = blk_sum(fv, scr) * (1.0f / D_);
        float d = fv - mean;
        float var = blk_sum(d * d, scr) * (1.0f / D_);
        fv = d * rsqrtf(var + EPS_) * w1[c];
    }
    float sy = fmaxf((y + 0.5f) * ((float)PH / OH) - 0.5f, 0.f);
    int y0 = min((int)floorf(sy), PH - 1);
    int y1 = min(y0 + 1, PH - 1);
    float ty = sy - (float)y0;
    float sx = fmaxf((x + 0.5f) * ((float)PW / OW) - 0.5f, 0.f);
    int x0 = min((int)floorf(sx), PW - 1);
    int x1 = min(x0 + 1, PW - 1);
    float tx = sx - (float)x0;
    const float* pb = prev + (size_t)b * prev_bstride;
    float v00 = pb[(size_t)(y0 * PW + x0) * D_ + c];
    float v01 = pb[(size_t)(y0 * PW + x1) * D_ + c];
    float v10 = pb[(size_t)(y1 * PW + x0) * D_ + c];
    float v11 = pb[(size_t)(y1 * PW + x1) * D_ + c];
    float top = v00 * (1.f - tx) + v01 * tx;
    float bot = v10 * (1.f - tx) + v11 * tx;
    out[(size_t)idx * D_ + c] = fv + (top * (1.f - ty) + bot * ty);
}

// ---------------- MFMA 3x3 conv: 32 pixels x 256 co per block ----------------
__global__ __launch_bounds__(256)
void k_conv_mfma(const float* __restrict__ in, const unsigned short* __restrict__ wb,
                 const float* __restrict__ bias, float* __restrict__ out, int H, int W) {
    int nxb = W >> 5;
    int bid = blockIdx.x;
    int x0 = (bid % nxb) << 5;
    int y  = (bid / nxb) % H;
    int b  = bid / (nxb * H);
    __shared__ unsigned short tile[3 * 34 * 256];   // [ky][cx 0..33][ci], swizzled by cx
    const float* ib = in + (size_t)b * H * W * 256;
    for (int t = threadIdx.x; t < 6528; t += 256) {
        int ci4 = (t & 63) << 2;
        int cxky = t >> 6;
        int cx = cxky % 34;
        int ky = cxky / 34;
        int gy = y + ky - 1;
        int gx = x0 + cx - 1;
        float4 v = make_float4(0.f, 0.f, 0.f, 0.f);
        if (gy >= 0 && gy < H && gx >= 0 && gx < W)
            v = *(const float4*)&ib[((size_t)gy * W + gx) * 256 + ci4];
        ushort4_ p;
        p.x = f2bf(v.x); p.y = f2bf(v.y); p.z = f2bf(v.z); p.w = f2bf(v.w);
        *(ushort4_*)&tile[(ky * 34 + cx) * 256 + (ci4 ^ ((cx & 7) << 3))] = p;
    }
    __syncthreads();
    int l = threadIdx.x & 63;
    int w = threadIdx.x >> 6;
    int rt = w & 1;
    int cb = (w >> 1) * 8;
    int kA = (l >> 4) * 8;
    f32x4 acc[8];
    #pragma unroll
    for (int i = 0; i < 8; ++i) acc[i] = (f32x4){0.f, 0.f, 0.f, 0.f};
    #pragma unroll
    for (int ky = 0; ky < 3; ++ky) {
        #pragma unroll
        for (int kx = 0; kx < 3; ++kx) {
            const unsigned short* ws = wb + (size_t)(ky * 3 + kx) * 65536;
            int cx = rt * 16 + (l & 15) + kx;
            const unsigned short* trow = &tile[(ky * 34 + cx) * 256];
            int swz = (cx & 7) << 3;
            #pragma unroll
            for (int ks = 0; ks < 8; ++ks) {
                short8 afv = *(const short8*)&trow[(ks * 32 + kA) ^ swz];
                #pragma unroll
                for (int ct = 0; ct < 8; ++ct) {
                    int co = (cb + ct) * 16 + (l & 15);
                    short8 bfv = *(const short8*)&ws[(size_t)co * 256 + ks * 32 + kA];
                    acc[ct] = __builtin_amdgcn_mfma_f32_16x16x32_bf16(afv, bfv, acc[ct], 0, 0, 0);
                }
            }
        }
    }
    size_t orow = ((size_t)b * H + y) * W;
    #pragma unroll
    for (int q = 0; q < 4; ++q) {
        int px = x0 + rt * 16 + (l >> 4) * 4 + q;
        #pragma unroll
        for (int ct = 0; ct < 8; ++ct) {
            int co = (cb + ct) * 16 + (l & 15);
            out[(orow + px) * 256 + co] = acc[ct][q] + bias[co];
        }
    }
}

// =====================================================================
// fused residual + LN + star-MLP via MFMA, LDS-staged weights
// 64 rows/block, 4 waves; weights chunked 64 hidden cols at a time.
// =====================================================================
__global__ __launch_bounds__(256)
void k_mlp_mfma(const float* __restrict__ a, const float* __restrict__ bsrc,
                const float* __restrict__ n2,
                const unsigned short* __restrict__ W1b, const unsigned short* __restrict__ W2b,
                const float* __restrict__ ssp, const float* __restrict__ sbp,
                float* __restrict__ out, int M) {
    __shared__ unsigned short buf[32768];  // 64KB: Xn(32KB) then [W1c|W2c]
    __shared__ unsigned short Hc[4096];    // 8KB: per-wave 16x64 H slice
    int r0 = blockIdx.x * 64;
    int tid = threadIdx.x;
    int w = tid >> 6;
    int l = tid & 63;
    float ss = ssp[0], sb = sbp[0];

    // ---- LN: wave w computes rows 16w..16w+15 -> Xn (buf[0:16384]) ----
    #pragma unroll 4
    for (int i = 0; i < 16; ++i) {
        int r = w * 16 + i;
        int row = r0 + r;
        float4 xa = make_float4(0.f,0.f,0.f,0.f), xb = xa;
        if (row < M) {
            xa = *(const float4*)&a[(size_t)row * 256 + l * 4];
            xb = *(const float4*)&bsrc[(size_t)row * 256 + l * 4];
        }
        float v0 = xa.x + xb.x, v1 = xa.y + xb.y, v2 = xa.z + xb.z, v3 = xa.w + xb.w;
        float s = v0 + v1 + v2 + v3;
        #pragma unroll
        for (int o = 32; o > 0; o >>= 1) s += __shfl_xor(s, o);
        float mean = s * (1.f / 256.f);
        float d0 = v0 - mean, d1 = v1 - mean, d2 = v2 - mean, d3 = v3 - mean;
        float vv = d0 * d0 + d1 * d1 + d2 * d2 + d3 * d3;
        #pragma unroll
        for (int o = 32; o > 0; o >>= 1) vv += __shfl_xor(vv, o);
        float rs = rsqrtf(vv * (1.f / 256.f) + EPS_);
        float4 nw = *(const float4*)&n2[l * 4];
        ushort4_ p;
        p.x = f2bf(d0 * rs * nw.x); p.y = f2bf(d1 * rs * nw.y);
        p.z = f2bf(d2 * rs * nw.z); p.w = f2bf(d3 * rs * nw.w);
        *(ushort4_*)&buf[r * 256 + ((l * 4) ^ ((r & 7) << 3))] = p;
    }
    __syncthreads();
    // ---- A frags -> regs (Xn then dead) ----
    int rA = 16 * w + (l & 15);
    int kA = (l >> 4) * 8;
    int swzA = (rA & 7) << 3;
    short8 af[8];
    #pragma unroll
    for (int ks = 0; ks < 8; ++ks)
        af[ks] = *(const short8*)&buf[rA * 256 + ((kA + ks * 32) ^ swzA)];
    __syncthreads();

    f32x4 oacc[16];
    #pragma unroll
    for (int i = 0; i < 16; ++i) oacc[i] = (f32x4){0.f,0.f,0.f,0.f};

    // ---- 16 chunks of 64 hidden cols ----
    for (int nc = 0; nc < 16; ++nc) {
        // stage W1 chunk [64 n x 256 k] into buf[0:16384]
        for (int g = tid; g < 2048; g += 256) {
            int n = g >> 5, e8 = g & 31;
            short8 p = *(const short8*)&W1b[(size_t)(nc * 64 + n) * 256 + e8 * 8];
            *(short8*)&buf[n * 256 + ((e8 * 8) ^ ((n & 7) << 3))] = p;
        }
        // stage W2 chunk [256 o x 64 k] into buf[16384:32768]
        for (int g = tid; g < 2048; g += 256) {
            int o = g >> 3, kb = g & 7;
            short8 p = *(const short8*)&W2b[(size_t)o * 1024 + nc * 64 + kb * 8];
            *(short8*)&buf[16384 + o * 64 + ((kb * 8) ^ ((o & 7) << 3))] = p;
        }
        __syncthreads();
        // fc1: 16 rows x 64 cols
        f32x4 hacc[4];
        #pragma unroll
        for (int i = 0; i < 4; ++i) hacc[i] = (f32x4){0.f,0.f,0.f,0.f};
        #pragma unroll
        for (int ks = 0; ks < 8; ++ks) {
            #pragma unroll
            for (int ct = 0; ct < 4; ++ct) {
                int n = ct * 16 + (l & 15);
                short8 bf = *(const short8*)&buf[n * 256 + ((kA + ks * 32) ^ ((n & 7) << 3))];
                hacc[ct] = __builtin_amdgcn_mfma_f32_16x16x32_bf16(af[ks], bf, hacc[ct], 0, 0, 0);
            }
        }
        // relu + star -> Hc (wave-private 16x64)
        #pragma unroll
        for (int ct = 0; ct < 4; ++ct) {
            #pragma unroll
            for (int q = 0; q < 4; ++q) {
                float hv = fmaxf(hacc[ct][q], 0.f);
                hv = ss * hv * hv + sb;
                int rr = (l >> 4) * 4 + q;
                int cc = ct * 16 + (l & 15);
                Hc[w * 1024 + rr * 64 + (cc ^ ((rr & 7) << 3))] = f2bf(hv);
            }
        }
        // fc2 partial: A = Hc [16 rows x 64 k], B = W2c
        #pragma unroll
        for (int ks2 = 0; ks2 < 2; ++ks2) {
            short8 af2 = *(const short8*)&Hc[w * 1024 + (l & 15) * 64 + ((kA + ks2 * 32) ^ (((l & 15) & 7) << 3))];
            #pragma unroll
            for (int ot = 0; ot < 16; ++ot) {
                int o = ot * 16 + (l & 15);
                short8 bf2 = *(const short8*)&buf[16384 + o * 64 + ((kA + ks2 * 32) ^ ((o & 7) << 3))];
                oacc[ot] = __builtin_amdgcn_mfma_f32_16x16x32_bf16(af2, bf2, oacc[ot], 0, 0, 0);
            }
        }
        __syncthreads();
    }
    // ---- epilogue: out = a + bsrc + fc2 ----
    #pragma unroll
    for (int q = 0; q < 4; ++q) {
        int row = r0 + 16 * w + (l >> 4) * 4 + q;
        if (row < M) {
            #pragma unroll
            for (int ot = 0; ot < 16; ++ot) {
                int col = ot * 16 + (l & 15);
                size_t off = (size_t)row * 256 + col;
                out[off] = a[off] + bsrc[off] + oacc[ot][q];
            }
        }
    }
}

// ---------------- launch ----------------
extern "C" void kernel_launch(void* const* d_in, const int* in_sizes, int n_in,
                              void* d_out, int out_size, void* d_ws, size_t ws_size,
                              hipStream_t stream) {
    const float* src   = (const float*)d_in[0];
    const float* pos   = (const float*)d_in[1];
    const float* fpn   = (const float*)d_in[2];
    const float* refp  = (const float*)d_in[3];
    const float* n1w   = (const float*)d_in[5];
    const float* n2w   = (const float*)d_in[6];
    const float* Wv    = (const float*)d_in[7];
    const float* bv    = (const float*)d_in[8];
    const float* Woff  = (const float*)d_in[9];
    const float* boff  = (const float*)d_in[10];
    const float* Wattn = (const float*)d_in[11];
    const float* battn = (const float*)d_in[12];
    const float* Wout  = (const float*)d_in[13];
    const float* bout  = (const float*)d_in[14];
    const float* convw = (const float*)d_in[15];
    const float* convb = (const float*)d_in[16];
    const float* fc1   = (const float*)d_in[17];
    const float* fc2   = (const float*)d_in[18];
    const float* ssp   = (const float*)d_in[19];
    const float* sbp   = (const float*)d_in[20];

    float* ws = (float*)d_ws;
    float* S2 = ws + OFF_S2;
    float* QB = ws + OFF_QB;
    float* VB = ws + OFF_VB;
    float* OB = ws + OFF_OB;
    float* AW = ws + OFF_AW;
    float* CA = ws + OFF_CA;
    float* CB = ws + OFF_CB;
    unsigned short* W1B = (unsigned short*)(ws + OFF_W1B);
    unsigned short* W2B = (unsigned short*)(ws + OFF_W2B);
    unsigned short* CWB = (unsigned short*)(ws + OFF_CWB);
    unsigned short* WVB = (unsigned short*)(ws + OFF_WVB);
    unsigned short* WOFB = (unsigned short*)(ws + OFF_WOFB);
    unsigned short* WATB = (unsigned short*)(ws + OFF_WATB);
    unsigned short* WOUB = (unsigned short*)(ws + OFF_WOUB);
    float* out = (float*)d_out;

    // 0. weight prep (bf16)
    k_cvt_pad<<<1024, 256, 0, stream>>>(fc1, W1B, 262144, 262144);
    k_cvt_pad<<<1024, 256, 0, stream>>>(fc2, W2B, 262144, 262144);
    k_conv_w_prep<<<(1769472 + 255) / 256, 256, 0, stream>>>(convw, CWB);
    k_cvt_pad<<<256, 256, 0, stream>>>(Wv, WVB, 65536, 65536);
    k_cvt_pad<<<192, 256, 0, stream>>>(Woff, WOFB, 49152, 49152);
    k_cvt_pad<<<128, 256, 0, stream>>>(Wattn, WATB, 24576, 32768);
    k_cvt_pad<<<256, 256, 0, stream>>>(Wout, WOUB, 65536, 65536);

    // 1. LN(src) -> S2 ; query -> QB
    k_ln_src<<<B_ * LQ_, 256, 0, stream>>>(src, pos, n1w, S2, QB);

    // 2. value projection (batched grid.y)
    k_gemm_mfma<4><<<dim3(SUMHW_ / 64, B_), 256, 0, stream>>>(
        S2 + (size_t)RTOK * D_, (long long)LQ_ * D_, WVB, bv,
        VB, (long long)SUMHW_ * D_, SUMHW_, 256);

    // 3. offsets / attention logits
    k_gemm_mfma<3><<<dim3((B_ * LQ_ + 63) / 64, 1), 256, 0, stream>>>(
        QB, 0, WOFB, boff, OB, 0, B_ * LQ_, 192);
    k_gemm_mfma<2><<<dim3((B_ * LQ_ + 63) / 64, 1), 256, 0, stream>>>(
        QB, 0, WATB, battn, AW, 0, B_ * LQ_, 96);
    k_softmax12<<<(B_ * LQ_ * NH_ + 255) / 256, 256, 0, stream>>>(AW, B_ * LQ_ * NH_);

    // 4. deformable sampling -> AT (reuse QB)
    k_sample<<<B_ * LQ_, 256, 0, stream>>>(VB, OB, AW, refp, QB);

    // 5. src2 = AT @ Wout^T + bout -> S2
    k_gemm_mfma<4><<<dim3((B_ * LQ_ + 63) / 64, 1), 256, 0, stream>>>(
        QB, 0, WOUB, bout, S2, 0, B_ * LQ_, 256);

    // 6. FPN fusion chain (convs via MFMA)
    k_build_f<<<B_ * 32 * 32, 256, 0, stream>>>(
        S2 + (size_t)(RTOK + 4096) * D_, (long long)LQ_ * D_, 0, n1w,
        S2 + (size_t)(RTOK + 5120) * D_, (long long)LQ_ * D_, 16, 16,
        CA, 32, 32);
    k_conv_mfma<<<1 * 32 * B_, 256, 0, stream>>>(CA, CWB, convb, CB, 32, 32);
    k_build_f<<<B_ * 64 * 64, 256, 0, stream>>>(
        S2 + (size_t)RTOK * D_, (long long)LQ_ * D_, 0, n1w,
        CB, (long long)32 * 32 * D_, 32, 32,
        CA, 64, 64);
    k_conv_mfma<<<2 * 64 * B_, 256, 0, stream>>>(CA, CWB + (size_t)9 * 65536, convb + D_, CB, 64, 64);
    k_build_f<<<B_ * 128 * 128, 256, 0, stream>>>(
        fpn, (long long)FH_ * FH_ * D_, 1, n1w,
        CB, (long long)64 * 64 * D_, 64, 64,
        CA, 128, 128);
    k_conv_mfma<<<4 * 128 * B_, 256, 0, stream>>>(CA, CWB + (size_t)18 * 65536, convb + 2 * D_, CB, 128, 128);

    // 7. fused residual + LN + MLP epilogues
    k_mlp_mfma<<<(B_ * LQ_ + 63) / 64, 256, 0, stream>>>(src, S2, n2w, W1B, W2B, ssp, sbp,
                                                         out, B_ * LQ_);
    k_mlp_mfma<<<(B_ * FH_ * FH_) / 64, 256, 0, stream>>>(fpn, CB, n2w, W1B, W2B, ssp, sbp,
                                                          out + (size_t)B_ * LQ_ * D_, B_ * FH_ * FH_);
}

// Round 5
// 959.461 us; speedup vs baseline: 3.3262x; 1.1768x over previous
//
#include <hip/hip_runtime.h>
#include <hip/hip_bf16.h>

// ---------------- constants ----------------
#define D_      256
#define NH_     8
#define HD_     32
#define NP_     4
#define NL_     3
#define RTOK    8
#define LQ_     5384
#define SUMHW_  5376
#define B_      2
#define FH_     128
#define HID_    1024
#define EPS_    1e-6f

// workspace offsets (in floats)
#define OFF_S2  0
#define OFF_QB  2756608
#define OFF_VB  5513216
#define OFF_OB  8265728
#define OFF_AW  10333184
#define OFF_CA  5513216
#define OFF_CB  13901824
// bf16 weight caches
#define OFF_W1B 22290432   // fc1  1024x256 bf16
#define OFF_W2B 22421504   // fc2  256x1024 bf16
#define OFF_CWB 22552576   // conv 27x256x256 bf16 (transposed)
#define OFF_WVB 23437312   // Wv   256x256 bf16
#define OFF_WOFB 23470080  // Woff 192x256 bf16
#define OFF_WATB 23494656  // Wattn 96->128x256 bf16 (zero-padded)
#define OFF_WOUB 23511040  // Wout 256x256 bf16
// total = 23,543,808 floats = 94.2 MB

typedef __attribute__((ext_vector_type(4))) float f32x4;
typedef __attribute__((ext_vector_type(8))) short short8;
typedef __attribute__((ext_vector_type(4))) unsigned short ushort4_;

__device__ __forceinline__ unsigned short f2bf(float f) {
    unsigned u = __float_as_uint(f);
    unsigned r = u + 0x7fff + ((u >> 16) & 1);   // RNE
    return (unsigned short)(r >> 16);
}

// ---------------- helpers ----------------
__device__ __forceinline__ float blk_sum(float v, float* scr) {
    #pragma unroll
    for (int o = 32; o > 0; o >>= 1) v += __shfl_down(v, o, 64);
    int w = threadIdx.x >> 6;
    if ((threadIdx.x & 63) == 0) scr[w] = v;
    __syncthreads();
    float s = scr[0] + scr[1] + scr[2] + scr[3];
    __syncthreads();
    return s;
}

// ---------------- weight prep: f32 -> bf16 (with zero pad) ----------------
__global__ __launch_bounds__(256)
void k_cvt_pad(const float* __restrict__ src, unsigned short* __restrict__ dst,
               int nreal, int ntot) {
    int i = blockIdx.x * 256 + threadIdx.x;
    if (i < ntot) dst[i] = (i < nreal) ? f2bf(src[i]) : (unsigned short)0;
}

// convw [27][256ci][256co] -> dst [27][256co][256ci] bf16
__global__ __launch_bounds__(256)
void k_conv_w_prep(const float* __restrict__ convw, unsigned short* __restrict__ dst) {
    int i = blockIdx.x * 256 + threadIdx.x;   // total 27*65536
    int ci = i & 255;
    int co = (i >> 8) & 255;
    int kk = i >> 16;
    dst[(size_t)kk * 65536 + co * 256 + ci] = f2bf(convw[(size_t)kk * 65536 + ci * 256 + co]);
}

// ---------------- LN(src) + query ----------------
__global__ __launch_bounds__(256)
void k_ln_src(const float* __restrict__ src, const float* __restrict__ pos,
              const float* __restrict__ w1, float* __restrict__ S2, float* __restrict__ QB) {
    size_t row = blockIdx.x;
    int c = threadIdx.x;
    __shared__ float scr[4];
    float v = src[row * D_ + c];
    float mean = blk_sum(v, scr) * (1.0f / D_);
    float d = v - mean;
    float var = blk_sum(d * d, scr) * (1.0f / D_);
    float y = d * rsqrtf(var + EPS_) * w1[c];
    S2[row * D_ + c] = y;
    QB[row * D_ + c] = y + pos[row * D_ + c];
}

// =====================================================================
// MFMA GEMM: C[M,N] = A[M,256] @ W[N,256]^T + bias
// =====================================================================
template<int NCHUNK>
__global__ __launch_bounds__(256)
void k_gemm_mfma(const float* __restrict__ A, long long a_bstride,
                 const unsigned short* __restrict__ Wb,
                 const float* __restrict__ bias, float* __restrict__ C,
                 long long c_bstride, int M, int N) {
    __shared__ unsigned short buf[16384];   // 32KB: A image, then W chunks
    int b = blockIdx.y;
    const float* Ab = A + (size_t)b * a_bstride;
    float* Cb = C + (size_t)b * c_bstride;
    int r0 = blockIdx.x * 64;
    int tid = threadIdx.x;
    int w = tid >> 6, l = tid & 63;

    // ---- stage A (f32 -> bf16, swizzled) ----
    for (int g = tid; g < 2048; g += 256) {
        int r = g >> 5, e8 = g & 31;
        int row = r0 + r;
        float4 v0 = make_float4(0.f,0.f,0.f,0.f), v1 = v0;
        if (row < M) {
            v0 = *(const float4*)&Ab[(size_t)row * 256 + e8 * 8];
            v1 = *(const float4*)&Ab[(size_t)row * 256 + e8 * 8 + 4];
        }
        short8 p;
        p[0]=f2bf(v0.x); p[1]=f2bf(v0.y); p[2]=f2bf(v0.z); p[3]=f2bf(v0.w);
        p[4]=f2bf(v1.x); p[5]=f2bf(v1.y); p[6]=f2bf(v1.z); p[7]=f2bf(v1.w);
        *(short8*)&buf[r * 256 + ((e8 * 8) ^ ((r & 7) << 3))] = p;
    }
    __syncthreads();
    // ---- A frags -> regs ----
    int rA = 16 * w + (l & 15);
    int kA = (l >> 4) * 8;
    int swzA = (rA & 7) << 3;
    short8 af[8];
    #pragma unroll
    for (int ks = 0; ks < 8; ++ks)
        af[ks] = *(const short8*)&buf[rA * 256 + ((kA + ks * 32) ^ swzA)];
    __syncthreads();

    // ---- chunk loop over outputs ----
    for (int nc = 0; nc < NCHUNK; ++nc) {
        for (int g = tid; g < 2048; g += 256) {
            int n = g >> 5, e8 = g & 31;
            short8 p = *(const short8*)&Wb[(size_t)(nc * 64 + n) * 256 + e8 * 8];
            *(short8*)&buf[n * 256 + ((e8 * 8) ^ ((n & 7) << 3))] = p;
        }
        __syncthreads();
        f32x4 acc[4];
        #pragma unroll
        for (int i = 0; i < 4; ++i) acc[i] = (f32x4){0.f,0.f,0.f,0.f};
        #pragma unroll
        for (int ks = 0; ks < 8; ++ks) {
            #pragma unroll
            for (int ct = 0; ct < 4; ++ct) {
                int n = ct * 16 + (l & 15);
                short8 bf = *(const short8*)&buf[n * 256 + ((kA + ks * 32) ^ ((n & 7) << 3))];
                acc[ct] = __builtin_amdgcn_mfma_f32_16x16x32_bf16(af[ks], bf, acc[ct], 0, 0, 0);
            }
        }
        #pragma unroll
        for (int ct = 0; ct < 4; ++ct) {
            int n = nc * 64 + ct * 16 + (l & 15);
            if (n < N) {
                float bb = bias ? bias[n] : 0.f;
                #pragma unroll
                for (int q = 0; q < 4; ++q) {
                    int row = r0 + 16 * w + (l >> 4) * 4 + q;
                    if (row < M) Cb[(size_t)row * N + n] = acc[ct][q] + bb;
                }
            }
        }
        __syncthreads();
    }
}

// ---------------- softmax over 12 ----------------
__global__ __launch_bounds__(256)
void k_softmax12(float* __restrict__ AW, int total) {
    int t = blockIdx.x * 256 + threadIdx.x;
    if (t >= total) return;
    float* p = AW + (size_t)t * 12;
    float m = p[0];
    #pragma unroll
    for (int i = 1; i < 12; ++i) m = fmaxf(m, p[i]);
    float s = 0.f;
    float e[12];
    #pragma unroll
    for (int i = 0; i < 12; ++i) { e[i] = __expf(p[i] - m); s += e[i]; }
    float inv = 1.f / s;
    #pragma unroll
    for (int i = 0; i < 12; ++i) p[i] = e[i] * inv;
}

// ---------------- deformable sampling ----------------
__global__ __launch_bounds__(256)
void k_sample(const float* __restrict__ VB, const float* __restrict__ OB,
              const float* __restrict__ AW, const float* __restrict__ refp,
              float* __restrict__ AT) {
    int bq = blockIdx.x;            // b*LQ + q
    int b  = bq / LQ_;
    int h  = threadIdx.x >> 5;
    int dd = threadIdx.x & 31;
    const float* off = OB + (size_t)bq * 192;
    const float* aw  = AW + (size_t)bq * 96;
    const float* rp  = refp + (size_t)bq * (NL_ * 2);
    const int HS[3] = {64, 32, 16};
    const int ST[3] = {0, 4096, 5120};
    float acc = 0.f;
    #pragma unroll
    for (int l = 0; l < NL_; ++l) {
        float rx = rp[l * 2 + 0], ry = rp[l * 2 + 1];
        int Wl = HS[l], Hl = HS[l];
        float fWl = (float)Wl, fHl = (float)Hl;
        const float* vbase = VB + ((size_t)b * SUMHW_ + ST[l]) * D_ + h * 32 + dd;
        #pragma unroll
        for (int p = 0; p < NP_; ++p) {
            int oi = ((h * NL_ + l) * NP_ + p) * 2;
            float locx = rx + off[oi]     / fWl;
            float locy = ry + off[oi + 1] / fHl;
            float x = locx * fWl - 0.5f;
            float y = locy * fHl - 0.5f;
            float x0f = floorf(x), y0f = floorf(y);
            float fx = x - x0f, fy = y - y0f;
            int x0 = (int)x0f, y0 = (int)y0f;
            float a = aw[(h * NL_ + l) * NP_ + p];
            float g = 0.f;
            if (x0 >= 0     && x0 < Wl     && y0 >= 0     && y0 < Hl)
                g += (1.f - fx) * (1.f - fy) * vbase[(size_t)(y0 * Wl + x0) * D_];
            if (x0 + 1 >= 0 && x0 + 1 < Wl && y0 >= 0     && y0 < Hl)
                g += fx * (1.f - fy) * vbase[(size_t)(y0 * Wl + x0 + 1) * D_];
            if (x0 >= 0     && x0 < Wl     && y0 + 1 >= 0 && y0 + 1 < Hl)
                g += (1.f - fx) * fy * vbase[(size_t)((y0 + 1) * Wl + x0) * D_];
            if (x0 + 1 >= 0 && x0 + 1 < Wl && y0 + 1 >= 0 && y0 + 1 < Hl)
                g += fx * fy * vbase[(size_t)((y0 + 1) * Wl + x0 + 1) * D_];
            acc += a * g;
        }
    }
    AT[(size_t)bq * D_ + threadIdx.x] = acc;
}

// ---------------- build f = feat (+optional LN) + bilinear-upsampled prev ----------------
__global__ __launch_bounds__(256)
void k_build_f(const float* __restrict__ feat, long long feat_bstride, int do_ln,
               const float* __restrict__ w1,
               const float* __restrict__ prev, long long prev_bstride, int PH, int PW,
               float* __restrict__ out, int OH, int OW) {
    int idx = blockIdx.x;
    int x = idx % OW;
    int y = (idx / OW) % OH;
    int b = idx / (OW * OH);
    int c = threadIdx.x;
    __shared__ float scr[4];
    float fv = feat[(size_t)b * feat_bstride + (size_t)(y * OW + x) * D_ + c];
    if (do_ln) {
        float mean = blk_sum(fv, scr) * (1.0f / D_);
        float d = fv - mean;
        float var = blk_sum(d * d, scr) * (1.0f / D_);
        fv = d * rsqrtf(var + EPS_) * w1[c];
    }
    float sy = fmaxf((y + 0.5f) * ((float)PH / OH) - 0.5f, 0.f);
    int y0 = min((int)floorf(sy), PH - 1);
    int y1 = min(y0 + 1, PH - 1);
    float ty = sy - (float)y0;
    float sx = fmaxf((x + 0.5f) * ((float)PW / OW) - 0.5f, 0.f);
    int x0 = min((int)floorf(sx), PW - 1);
    int x1 = min(x0 + 1, PW - 1);
    float tx = sx - (float)x0;
    const float* pb = prev + (size_t)b * prev_bstride;
    float v00 = pb[(size_t)(y0 * PW + x0) * D_ + c];
    float v01 = pb[(size_t)(y0 * PW + x1) * D_ + c];
    float v10 = pb[(size_t)(y1 * PW + x0) * D_ + c];
    float v11 = pb[(size_t)(y1 * PW + x1) * D_ + c];
    float top = v00 * (1.f - tx) + v01 * tx;
    float bot = v10 * (1.f - tx) + v11 * tx;
    out[(size_t)idx * D_ + c] = fv + (top * (1.f - ty) + bot * ty);
}

// =====================================================================
// MFMA 3x3 conv: SW-pixel row strip x 256 co per block, ky-outer row
// staging, LDS weight chunks (64 co x 256 ci per stage).
// =====================================================================
template<int SW>
__global__ __launch_bounds__(256)
void k_conv_mfma(const float* __restrict__ in, const unsigned short* __restrict__ wb,
                 const float* __restrict__ bias, float* __restrict__ out, int H, int W) {
    constexpr int CX = SW + 2;
    constexpr int NCT = (SW == 64) ? 4 : 2;
    __shared__ unsigned short tile[CX * 256];   // current input row (bf16, swizzled by cx)
    __shared__ unsigned short wbuf[64 * 256];   // 64 co x 256 ci (swizzled by co)
    int nxb = W / SW;
    int bid = blockIdx.x;
    int x0 = (bid % nxb) * SW;
    int y  = (bid / nxb) % H;
    int b  = bid / (nxb * H);
    int tid = threadIdx.x, w = tid >> 6, l = tid & 63;
    const float* ib = in + (size_t)b * H * W * 256;

    int RT    = (SW == 64) ? w : (w & 1);        // 16-pixel row tile
    int ctoff = (SW == 64) ? 0 : ((w >> 1) * 2); // co-subtile base within 64-chunk
    int kA = (l >> 4) * 8;

    f32x4 acc[4 * NCT];
    #pragma unroll
    for (int i = 0; i < 4 * NCT; ++i) acc[i] = (f32x4){0.f, 0.f, 0.f, 0.f};

    for (int ky = 0; ky < 3; ++ky) {
        int gy = y + ky - 1;
        __syncthreads();
        // stage input row (f32 -> bf16, swizzled)
        for (int t = tid; t < CX * 32; t += 256) {
            int cx = t >> 5;
            int e8 = (t & 31) * 8;
            int gx = x0 + cx - 1;
            float4 v0 = make_float4(0.f,0.f,0.f,0.f), v1 = v0;
            if (gy >= 0 && gy < H && gx >= 0 && gx < W) {
                v0 = *(const float4*)&ib[((size_t)gy * W + gx) * 256 + e8];
                v1 = *(const float4*)&ib[((size_t)gy * W + gx) * 256 + e8 + 4];
            }
            short8 p;
            p[0]=f2bf(v0.x); p[1]=f2bf(v0.y); p[2]=f2bf(v0.z); p[3]=f2bf(v0.w);
            p[4]=f2bf(v1.x); p[5]=f2bf(v1.y); p[6]=f2bf(v1.z); p[7]=f2bf(v1.w);
            *(short8*)&tile[cx * 256 + (e8 ^ ((cx & 7) << 3))] = p;
        }
        __syncthreads();
        for (int kx = 0; kx < 3; ++kx) {
            // A frags -> regs (reused across all 4 co-chunks)
            short8 af[8];
            int cx = RT * 16 + (l & 15) + kx;
            int swz = (cx & 7) << 3;
            #pragma unroll
            for (int ks = 0; ks < 8; ++ks)
                af[ks] = *(const short8*)&tile[cx * 256 + ((ks * 32 + kA) ^ swz)];
            const unsigned short* wt = wb + (size_t)(ky * 3 + kx) * 65536;
            for (int nc = 0; nc < 4; ++nc) {
                __syncthreads();
                for (int g = tid; g < 2048; g += 256) {
                    int n = g >> 5, e8 = (g & 31) * 8;
                    short8 p = *(const short8*)&wt[(size_t)(nc * 64 + n) * 256 + e8];
                    *(short8*)&wbuf[n * 256 + (e8 ^ ((n & 7) << 3))] = p;
                }
                __syncthreads();
                #pragma unroll
                for (int ks = 0; ks < 8; ++ks) {
                    #pragma unroll
                    for (int j = 0; j < NCT; ++j) {
                        int n = (ctoff + j) * 16 + (l & 15);
                        short8 bf = *(const short8*)&wbuf[n * 256 + ((ks * 32 + kA) ^ ((n & 7) << 3))];
                        acc[nc * NCT + j] = __builtin_amdgcn_mfma_f32_16x16x32_bf16(af[ks], bf, acc[nc * NCT + j], 0, 0, 0);
                    }
                }
            }
        }
    }
    size_t orow = ((size_t)b * H + y) * W;
    #pragma unroll
    for (int q = 0; q < 4; ++q) {
        int px = x0 + RT * 16 + (l >> 4) * 4 + q;
        #pragma unroll
        for (int nc = 0; nc < 4; ++nc) {
            #pragma unroll
            for (int j = 0; j < NCT; ++j) {
                int n = nc * 64 + (ctoff + j) * 16 + (l & 15);
                out[(orow + px) * 256 + n] = acc[nc * NCT + j][q] + bias[n];
            }
        }
    }
}

// =====================================================================
// fused residual + LN + star-MLP via MFMA, LDS-staged weights
// =====================================================================
__global__ __launch_bounds__(256)
void k_mlp_mfma(const float* __restrict__ a, const float* __restrict__ bsrc,
                const float* __restrict__ n2,
                const unsigned short* __restrict__ W1b, const unsigned short* __restrict__ W2b,
                const float* __restrict__ ssp, const float* __restrict__ sbp,
                float* __restrict__ out, int M) {
    __shared__ unsigned short buf[32768];  // 64KB: Xn(32KB) then [W1c|W2c]
    __shared__ unsigned short Hc[4096];    // 8KB: per-wave 16x64 H slice
    int r0 = blockIdx.x * 64;
    int tid = threadIdx.x;
    int w = tid >> 6;
    int l = tid & 63;
    float ss = ssp[0], sb = sbp[0];

    #pragma unroll 4
    for (int i = 0; i < 16; ++i) {
        int r = w * 16 + i;
        int row = r0 + r;
        float4 xa = make_float4(0.f,0.f,0.f,0.f), xb = xa;
        if (row < M) {
            xa = *(const float4*)&a[(size_t)row * 256 + l * 4];
            xb = *(const float4*)&bsrc[(size_t)row * 256 + l * 4];
        }
        float v0 = xa.x + xb.x, v1 = xa.y + xb.y, v2 = xa.z + xb.z, v3 = xa.w + xb.w;
        float s = v0 + v1 + v2 + v3;
        #pragma unroll
        for (int o = 32; o > 0; o >>= 1) s += __shfl_xor(s, o);
        float mean = s * (1.f / 256.f);
        float d0 = v0 - mean, d1 = v1 - mean, d2 = v2 - mean, d3 = v3 - mean;
        float vv = d0 * d0 + d1 * d1 + d2 * d2 + d3 * d3;
        #pragma unroll
        for (int o = 32; o > 0; o >>= 1) vv += __shfl_xor(vv, o);
        float rs = rsqrtf(vv * (1.f / 256.f) + EPS_);
        float4 nw = *(const float4*)&n2[l * 4];
        ushort4_ p;
        p.x = f2bf(d0 * rs * nw.x); p.y = f2bf(d1 * rs * nw.y);
        p.z = f2bf(d2 * rs * nw.z); p.w = f2bf(d3 * rs * nw.w);
        *(ushort4_*)&buf[r * 256 + ((l * 4) ^ ((r & 7) << 3))] = p;
    }
    __syncthreads();
    int rA = 16 * w + (l & 15);
    int kA = (l >> 4) * 8;
    int swzA = (rA & 7) << 3;
    short8 af[8];
    #pragma unroll
    for (int ks = 0; ks < 8; ++ks)
        af[ks] = *(const short8*)&buf[rA * 256 + ((kA + ks * 32) ^ swzA)];
    __syncthreads();

    f32x4 oacc[16];
    #pragma unroll
    for (int i = 0; i < 16; ++i) oacc[i] = (f32x4){0.f,0.f,0.f,0.f};

    for (int nc = 0; nc < 16; ++nc) {
        for (int g = tid; g < 2048; g += 256) {
            int n = g >> 5, e8 = g & 31;
            short8 p = *(const short8*)&W1b[(size_t)(nc * 64 + n) * 256 + e8 * 8];
            *(short8*)&buf[n * 256 + ((e8 * 8) ^ ((n & 7) << 3))] = p;
        }
        for (int g = tid; g < 2048; g += 256) {
            int o = g >> 3, kb = g & 7;
            short8 p = *(const short8*)&W2b[(size_t)o * 1024 + nc * 64 + kb * 8];
            *(short8*)&buf[16384 + o * 64 + ((kb * 8) ^ ((o & 7) << 3))] = p;
        }
        __syncthreads();
        f32x4 hacc[4];
        #pragma unroll
        for (int i = 0; i < 4; ++i) hacc[i] = (f32x4){0.f,0.f,0.f,0.f};
        #pragma unroll
        for (int ks = 0; ks < 8; ++ks) {
            #pragma unroll
            for (int ct = 0; ct < 4; ++ct) {
                int n = ct * 16 + (l & 15);
                short8 bf = *(const short8*)&buf[n * 256 + ((kA + ks * 32) ^ ((n & 7) << 3))];
                hacc[ct] = __builtin_amdgcn_mfma_f32_16x16x32_bf16(af[ks], bf, hacc[ct], 0, 0, 0);
            }
        }
        #pragma unroll
        for (int ct = 0; ct < 4; ++ct) {
            #pragma unroll
            for (int q = 0; q < 4; ++q) {
                float hv = fmaxf(hacc[ct][q], 0.f);
                hv = ss * hv * hv + sb;
                int rr = (l >> 4) * 4 + q;
                int cc = ct * 16 + (l & 15);
                Hc[w * 1024 + rr * 64 + (cc ^ ((rr & 7) << 3))] = f2bf(hv);
            }
        }
        #pragma unroll
        for (int ks2 = 0; ks2 < 2; ++ks2) {
            short8 af2 = *(const short8*)&Hc[w * 1024 + (l & 15) * 64 + ((kA + ks2 * 32) ^ (((l & 15) & 7) << 3))];
            #pragma unroll
            for (int ot = 0; ot < 16; ++ot) {
                int o = ot * 16 + (l & 15);
                short8 bf2 = *(const short8*)&buf[16384 + o * 64 + ((kA + ks2 * 32) ^ ((o & 7) << 3))];
                oacc[ot] = __builtin_amdgcn_mfma_f32_16x16x32_bf16(af2, bf2, oacc[ot], 0, 0, 0);
            }
        }
        __syncthreads();
    }
    #pragma unroll
    for (int q = 0; q < 4; ++q) {
        int row = r0 + 16 * w + (l >> 4) * 4 + q;
        if (row < M) {
            #pragma unroll
            for (int ot = 0; ot < 16; ++ot) {
                int col = ot * 16 + (l & 15);
                size_t off = (size_t)row * 256 + col;
                out[off] = a[off] + bsrc[off] + oacc[ot][q];
            }
        }
    }
}

// ---------------- launch ----------------
extern "C" void kernel_launch(void* const* d_in, const int* in_sizes, int n_in,
                              void* d_out, int out_size, void* d_ws, size_t ws_size,
                              hipStream_t stream) {
    const float* src   = (const float*)d_in[0];
    const float* pos   = (const float*)d_in[1];
    const float* fpn   = (const float*)d_in[2];
    const float* refp  = (const float*)d_in[3];
    const float* n1w   = (const float*)d_in[5];
    const float* n2w   = (const float*)d_in[6];
    const float* Wv    = (const float*)d_in[7];
    const float* bv    = (const float*)d_in[8];
    const float* Woff  = (const float*)d_in[9];
    const float* boff  = (const float*)d_in[10];
    const float* Wattn = (const float*)d_in[11];
    const float* battn = (const float*)d_in[12];
    const float* Wout  = (const float*)d_in[13];
    const float* bout  = (const float*)d_in[14];
    const float* convw = (const float*)d_in[15];
    const float* convb = (const float*)d_in[16];
    const float* fc1   = (const float*)d_in[17];
    const float* fc2   = (const float*)d_in[18];
    const float* ssp   = (const float*)d_in[19];
    const float* sbp   = (const float*)d_in[20];

    float* ws = (float*)d_ws;
    float* S2 = ws + OFF_S2;
    float* QB = ws + OFF_QB;
    float* VB = ws + OFF_VB;
    float* OB = ws + OFF_OB;
    float* AW = ws + OFF_AW;
    float* CA = ws + OFF_CA;
    float* CB = ws + OFF_CB;
    unsigned short* W1B = (unsigned short*)(ws + OFF_W1B);
    unsigned short* W2B = (unsigned short*)(ws + OFF_W2B);
    unsigned short* CWB = (unsigned short*)(ws + OFF_CWB);
    unsigned short* WVB = (unsigned short*)(ws + OFF_WVB);
    unsigned short* WOFB = (unsigned short*)(ws + OFF_WOFB);
    unsigned short* WATB = (unsigned short*)(ws + OFF_WATB);
    unsigned short* WOUB = (unsigned short*)(ws + OFF_WOUB);
    float* out = (float*)d_out;

    // 0. weight prep (bf16)
    k_cvt_pad<<<1024, 256, 0, stream>>>(fc1, W1B, 262144, 262144);
    k_cvt_pad<<<1024, 256, 0, stream>>>(fc2, W2B, 262144, 262144);
    k_conv_w_prep<<<(1769472 + 255) / 256, 256, 0, stream>>>(convw, CWB);
    k_cvt_pad<<<256, 256, 0, stream>>>(Wv, WVB, 65536, 65536);
    k_cvt_pad<<<192, 256, 0, stream>>>(Woff, WOFB, 49152, 49152);
    k_cvt_pad<<<128, 256, 0, stream>>>(Wattn, WATB, 24576, 32768);
    k_cvt_pad<<<256, 256, 0, stream>>>(Wout, WOUB, 65536, 65536);

    // 1. LN(src) -> S2 ; query -> QB
    k_ln_src<<<B_ * LQ_, 256, 0, stream>>>(src, pos, n1w, S2, QB);

    // 2. value projection
    k_gemm_mfma<4><<<dim3(SUMHW_ / 64, B_), 256, 0, stream>>>(
        S2 + (size_t)RTOK * D_, (long long)LQ_ * D_, WVB, bv,
        VB, (long long)SUMHW_ * D_, SUMHW_, 256);

    // 3. offsets / attention logits
    k_gemm_mfma<3><<<dim3((B_ * LQ_ + 63) / 64, 1), 256, 0, stream>>>(
        QB, 0, WOFB, boff, OB, 0, B_ * LQ_, 192);
    k_gemm_mfma<2><<<dim3((B_ * LQ_ + 63) / 64, 1), 256, 0, stream>>>(
        QB, 0, WATB, battn, AW, 0, B_ * LQ_, 96);
    k_softmax12<<<(B_ * LQ_ * NH_ + 255) / 256, 256, 0, stream>>>(AW, B_ * LQ_ * NH_);

    // 4. deformable sampling -> AT (reuse QB)
    k_sample<<<B_ * LQ_, 256, 0, stream>>>(VB, OB, AW, refp, QB);

    // 5. src2 = AT @ Wout^T + bout -> S2
    k_gemm_mfma<4><<<dim3((B_ * LQ_ + 63) / 64, 1), 256, 0, stream>>>(
        QB, 0, WOUB, bout, S2, 0, B_ * LQ_, 256);

    // 6. FPN fusion chain (convs via MFMA, LDS-staged weights)
    k_build_f<<<B_ * 32 * 32, 256, 0, stream>>>(
        S2 + (size_t)(RTOK + 4096) * D_, (long long)LQ_ * D_, 0, n1w,
        S2 + (size_t)(RTOK + 5120) * D_, (long long)LQ_ * D_, 16, 16,
        CA, 32, 32);
    k_conv_mfma<32><<<32 * B_, 256, 0, stream>>>(CA, CWB, convb, CB, 32, 32);
    k_build_f<<<B_ * 64 * 64, 256, 0, stream>>>(
        S2 + (size_t)RTOK * D_, (long long)LQ_ * D_, 0, n1w,
        CB, (long long)32 * 32 * D_, 32, 32,
        CA, 64, 64);
    k_conv_mfma<64><<<64 * B_, 256, 0, stream>>>(CA, CWB + (size_t)9 * 65536, convb + D_, CB, 64, 64);
    k_build_f<<<B_ * 128 * 128, 256, 0, stream>>>(
        fpn, (long long)FH_ * FH_ * D_, 1, n1w,
        CB, (long long)64 * 64 * D_, 64, 64,
        CA, 128, 128);
    k_conv_mfma<64><<<2 * 128 * B_, 256, 0, stream>>>(CA, CWB + (size_t)18 * 65536, convb + 2 * D_, CB, 128, 128);

    // 7. fused residual + LN + MLP epilogues
    k_mlp_mfma<<<(B_ * LQ_ + 63) / 64, 256, 0, stream>>>(src, S2, n2w, W1B, W2B, ssp, sbp,
                                                         out, B_ * LQ_);
    k_mlp_mfma<<<(B_ * FH_ * FH_) / 64, 256, 0, stream>>>(fpn, CB, n2w, W1B, W2B, ssp, sbp,
                                                          out + (size_t)B_ * LQ_ * D_, B_ * FH_ * FH_);
}

// Round 6
// 823.655 us; speedup vs baseline: 3.8747x; 1.1649x over previous
//
#include <hip/hip_runtime.h>
#include <hip/hip_bf16.h>

// ---------------- constants ----------------
#define D_      256
#define NH_     8
#define HD_     32
#define NP_     4
#define NL_     3
#define RTOK    8
#define LQ_     5384
#define SUMHW_  5376
#define B_      2
#define FH_     128
#define HID_    1024
#define EPS_    1e-6f

// workspace offsets (in floats)
#define OFF_S2  0
#define OFF_QB  2756608
#define OFF_VB  5513216
#define OFF_OB  8265728
#define OFF_AW  10333184
#define OFF_CA  5513216
#define OFF_CB  13901824
// bf16 weight caches
#define OFF_W1B 22290432   // fc1  1024x256 bf16
#define OFF_W2B 22421504   // fc2  256x1024 bf16
#define OFF_CWB 22552576   // conv 27x256x256 bf16 (transposed)
#define OFF_WVB 23437312   // Wv   256x256 bf16
#define OFF_WOFB 23470080  // Woff 192x256 bf16
#define OFF_WATB 23494656  // Wattn 96->128x256 bf16 (zero-padded)
#define OFF_WOUB 23511040  // Wout 256x256 bf16
// total = 23,543,808 floats = 94.2 MB

typedef __attribute__((ext_vector_type(4))) float f32x4;
typedef __attribute__((ext_vector_type(8))) short short8;
typedef __attribute__((ext_vector_type(4))) unsigned short ushort4_;

__device__ __forceinline__ unsigned short f2bf(float f) {
    unsigned u = __float_as_uint(f);
    unsigned r = u + 0x7fff + ((u >> 16) & 1);   // RNE
    return (unsigned short)(r >> 16);
}

// ---------------- helpers ----------------
__device__ __forceinline__ float blk_sum(float v, float* scr) {
    #pragma unroll
    for (int o = 32; o > 0; o >>= 1) v += __shfl_down(v, o, 64);
    int w = threadIdx.x >> 6;
    if ((threadIdx.x & 63) == 0) scr[w] = v;
    __syncthreads();
    float s = scr[0] + scr[1] + scr[2] + scr[3];
    __syncthreads();
    return s;
}

// ---------------- weight prep ----------------
__global__ __launch_bounds__(256)
void k_cvt_pad(const float* __restrict__ src, unsigned short* __restrict__ dst,
               int nreal, int ntot) {
    int i = blockIdx.x * 256 + threadIdx.x;
    if (i < ntot) dst[i] = (i < nreal) ? f2bf(src[i]) : (unsigned short)0;
}

// convw [27][256ci][256co] -> dst [27][256co][256ci] bf16
__global__ __launch_bounds__(256)
void k_conv_w_prep(const float* __restrict__ convw, unsigned short* __restrict__ dst) {
    int i = blockIdx.x * 256 + threadIdx.x;   // total 27*65536
    int ci = i & 255;
    int co = (i >> 8) & 255;
    int kk = i >> 16;
    dst[(size_t)kk * 65536 + co * 256 + ci] = f2bf(convw[(size_t)kk * 65536 + ci * 256 + co]);
}

// ---------------- LN(src) + query ----------------
__global__ __launch_bounds__(256)
void k_ln_src(const float* __restrict__ src, const float* __restrict__ pos,
              const float* __restrict__ w1, float* __restrict__ S2, float* __restrict__ QB) {
    size_t row = blockIdx.x;
    int c = threadIdx.x;
    __shared__ float scr[4];
    float v = src[row * D_ + c];
    float mean = blk_sum(v, scr) * (1.0f / D_);
    float d = v - mean;
    float var = blk_sum(d * d, scr) * (1.0f / D_);
    float y = d * rsqrtf(var + EPS_) * w1[c];
    S2[row * D_ + c] = y;
    QB[row * D_ + c] = y + pos[row * D_ + c];
}

// =====================================================================
// MFMA GEMM: C[M,N] = A[M,256] @ W[N,256]^T + bias
// (n&15) XOR swizzle + reg-prefetched weight chunks (T14)
// =====================================================================
template<int NCHUNK>
__global__ __launch_bounds__(256)
void k_gemm_mfma(const float* __restrict__ A, long long a_bstride,
                 const unsigned short* __restrict__ Wb,
                 const float* __restrict__ bias, float* __restrict__ C,
                 long long c_bstride, int M, int N) {
    __shared__ unsigned short buf[16384];   // 32KB: A image, then W chunks
    int b = blockIdx.y;
    const float* Ab = A + (size_t)b * a_bstride;
    float* Cb = C + (size_t)b * c_bstride;
    int r0 = blockIdx.x * 64;
    int tid = threadIdx.x;
    int w = tid >> 6, l = tid & 63;

    // prefetch W chunk 0 (hides under A staging)
    short8 R[8];
    {
        const short8* p = (const short8*)Wb;
        #pragma unroll
        for (int i = 0; i < 8; ++i) R[i] = p[tid + i * 256];
    }

    // ---- stage A (f32 -> bf16, swizzled &15) ----
    for (int g = tid; g < 2048; g += 256) {
        int r = g >> 5, e8 = g & 31;
        int row = r0 + r;
        float4 v0 = make_float4(0.f,0.f,0.f,0.f), v1 = v0;
        if (row < M) {
            v0 = *(const float4*)&Ab[(size_t)row * 256 + e8 * 8];
            v1 = *(const float4*)&Ab[(size_t)row * 256 + e8 * 8 + 4];
        }
        short8 p;
        p[0]=f2bf(v0.x); p[1]=f2bf(v0.y); p[2]=f2bf(v0.z); p[3]=f2bf(v0.w);
        p[4]=f2bf(v1.x); p[5]=f2bf(v1.y); p[6]=f2bf(v1.z); p[7]=f2bf(v1.w);
        *(short8*)&buf[r * 256 + ((e8 * 8) ^ ((r & 15) << 3))] = p;
    }
    __syncthreads();
    // ---- A frags -> regs ----
    int rA = 16 * w + (l & 15);
    int kA = (l >> 4) * 8;
    int swzA = (rA & 15) << 3;
    short8 af[8];
    #pragma unroll
    for (int ks = 0; ks < 8; ++ks)
        af[ks] = *(const short8*)&buf[rA * 256 + ((kA + ks * 32) ^ swzA)];
    __syncthreads();

    // ---- chunk loop over outputs ----
    for (int nc = 0; nc < NCHUNK; ++nc) {
        // write prefetched chunk -> LDS
        #pragma unroll
        for (int i = 0; i < 8; ++i) {
            int g = tid + i * 256;
            int n = g >> 5, e8 = (g & 31) * 8;
            *(short8*)&buf[n * 256 + (e8 ^ ((n & 15) << 3))] = R[i];
        }
        // issue next chunk's loads (stay in flight across barrier)
        if (nc + 1 < NCHUNK) {
            const short8* p = (const short8*)(Wb + (size_t)(nc + 1) * 16384);
            #pragma unroll
            for (int i = 0; i < 8; ++i) R[i] = p[tid + i * 256];
        }
        __syncthreads();
        f32x4 acc[4];
        #pragma unroll
        for (int i = 0; i < 4; ++i) acc[i] = (f32x4){0.f,0.f,0.f,0.f};
        #pragma unroll
        for (int ks = 0; ks < 8; ++ks) {
            #pragma unroll
            for (int ct = 0; ct < 4; ++ct) {
                int n = ct * 16 + (l & 15);
                short8 bf = *(const short8*)&buf[n * 256 + ((kA + ks * 32) ^ ((n & 15) << 3))];
                acc[ct] = __builtin_amdgcn_mfma_f32_16x16x32_bf16(af[ks], bf, acc[ct], 0, 0, 0);
            }
        }
        #pragma unroll
        for (int ct = 0; ct < 4; ++ct) {
            int n = nc * 64 + ct * 16 + (l & 15);
            if (n < N) {
                float bb = bias ? bias[n] : 0.f;
                #pragma unroll
                for (int q = 0; q < 4; ++q) {
                    int row = r0 + 16 * w + (l >> 4) * 4 + q;
                    if (row < M) Cb[(size_t)row * N + n] = acc[ct][q] + bb;
                }
            }
        }
        __syncthreads();
    }
}

// ---------------- softmax over 12 ----------------
__global__ __launch_bounds__(256)
void k_softmax12(float* __restrict__ AW, int total) {
    int t = blockIdx.x * 256 + threadIdx.x;
    if (t >= total) return;
    float* p = AW + (size_t)t * 12;
    float m = p[0];
    #pragma unroll
    for (int i = 1; i < 12; ++i) m = fmaxf(m, p[i]);
    float s = 0.f;
    float e[12];
    #pragma unroll
    for (int i = 0; i < 12; ++i) { e[i] = __expf(p[i] - m); s += e[i]; }
    float inv = 1.f / s;
    #pragma unroll
    for (int i = 0; i < 12; ++i) p[i] = e[i] * inv;
}

// ---------------- deformable sampling ----------------
__global__ __launch_bounds__(256)
void k_sample(const float* __restrict__ VB, const float* __restrict__ OB,
              const float* __restrict__ AW, const float* __restrict__ refp,
              float* __restrict__ AT) {
    int bq = blockIdx.x;            // b*LQ + q
    int b  = bq / LQ_;
    int h  = threadIdx.x >> 5;
    int dd = threadIdx.x & 31;
    const float* off = OB + (size_t)bq * 192;
    const float* aw  = AW + (size_t)bq * 96;
    const float* rp  = refp + (size_t)bq * (NL_ * 2);
    const int HS[3] = {64, 32, 16};
    const int ST[3] = {0, 4096, 5120};
    float acc = 0.f;
    #pragma unroll
    for (int l = 0; l < NL_; ++l) {
        float rx = rp[l * 2 + 0], ry = rp[l * 2 + 1];
        int Wl = HS[l], Hl = HS[l];
        float fWl = (float)Wl, fHl = (float)Hl;
        const float* vbase = VB + ((size_t)b * SUMHW_ + ST[l]) * D_ + h * 32 + dd;
        #pragma unroll
        for (int p = 0; p < NP_; ++p) {
            int oi = ((h * NL_ + l) * NP_ + p) * 2;
            float locx = rx + off[oi]     / fWl;
            float locy = ry + off[oi + 1] / fHl;
            float x = locx * fWl - 0.5f;
            float y = locy * fHl - 0.5f;
            float x0f = floorf(x), y0f = floorf(y);
            float fx = x - x0f, fy = y - y0f;
            int x0 = (int)x0f, y0 = (int)y0f;
            float a = aw[(h * NL_ + l) * NP_ + p];
            float g = 0.f;
            if (x0 >= 0     && x0 < Wl     && y0 >= 0     && y0 < Hl)
                g += (1.f - fx) * (1.f - fy) * vbase[(size_t)(y0 * Wl + x0) * D_];
            if (x0 + 1 >= 0 && x0 + 1 < Wl && y0 >= 0     && y0 < Hl)
                g += fx * (1.f - fy) * vbase[(size_t)(y0 * Wl + x0 + 1) * D_];
            if (x0 >= 0     && x0 < Wl     && y0 + 1 >= 0 && y0 + 1 < Hl)
                g += (1.f - fx) * fy * vbase[(size_t)((y0 + 1) * Wl + x0) * D_];
            if (x0 + 1 >= 0 && x0 + 1 < Wl && y0 + 1 >= 0 && y0 + 1 < Hl)
                g += fx * fy * vbase[(size_t)((y0 + 1) * Wl + x0 + 1) * D_];
            acc += a * g;
        }
    }
    AT[(size_t)bq * D_ + threadIdx.x] = acc;
}

// ---------------- build f = feat (+optional LN) + bilinear-upsampled prev ----------------
__global__ __launch_bounds__(256)
void k_build_f(const float* __restrict__ feat, long long feat_bstride, int do_ln,
               const float* __restrict__ w1,
               const float* __restrict__ prev, long long prev_bstride, int PH, int PW,
               float* __restrict__ out, int OH, int OW) {
    int idx = blockIdx.x;
    int x = idx % OW;
    int y = (idx / OW) % OH;
    int b = idx / (OW * OH);
    int c = threadIdx.x;
    __shared__ float scr[4];
    float fv = feat[(size_t)b * feat_bstride + (size_t)(y * OW + x) * D_ + c];
    if (do_ln) {
        float mean = blk_sum(fv, scr) * (1.0f / D_);
        float d = fv - mean;
        float var = blk_sum(d * d, scr) * (1.0f / D_);
        fv = d * rsqrtf(var + EPS_) * w1[c];
    }
    float sy = fmaxf((y + 0.5f) * ((float)PH / OH) - 0.5f, 0.f);
    int y0 = min((int)floorf(sy), PH - 1);
    int y1 = min(y0 + 1, PH - 1);
    float ty = sy - (float)y0;
    float sx = fmaxf((x + 0.5f) * ((float)PW / OW) - 0.5f, 0.f);
    int x0 = min((int)floorf(sx), PW - 1);
    int x1 = min(x0 + 1, PW - 1);
    float tx = sx - (float)x0;
    const float* pb = prev + (size_t)b * prev_bstride;
    float v00 = pb[(size_t)(y0 * PW + x0) * D_ + c];
    float v01 = pb[(size_t)(y0 * PW + x1) * D_ + c];
    float v10 = pb[(size_t)(y1 * PW + x0) * D_ + c];
    float v11 = pb[(size_t)(y1 * PW + x1) * D_ + c];
    float top = v00 * (1.f - tx) + v01 * tx;
    float bot = v10 * (1.f - tx) + v11 * tx;
    out[(size_t)idx * D_ + c] = fv + (top * (1.f - ty) + bot * ty);
}

// =====================================================================
// MFMA 3x3 conv: SW-pixel row strip x 256 co per block.
// Weight chunks consumed LINEARLY (chunk c = wb + c*16384), reg-prefetch
// one chunk ahead; (n&15) XOR swizzle on all LDS tiles.
// =====================================================================
template<int SW>
__global__ __launch_bounds__(256)
void k_conv_mfma(const float* __restrict__ in, const unsigned short* __restrict__ wb,
                 const float* __restrict__ bias, float* __restrict__ out, int H, int W) {
    constexpr int CX = SW + 2;
    constexpr int NCT = (SW == 64) ? 4 : 2;
    __shared__ unsigned short tile[CX * 256];   // current input row (bf16, swizzled by cx)
    __shared__ unsigned short wbuf[64 * 256];   // 64 co x 256 ci (swizzled by co)
    int nxb = W / SW;
    int bid = blockIdx.x;
    int x0 = (bid % nxb) * SW;
    int y  = (bid / nxb) % H;
    int b  = bid / (nxb * H);
    int tid = threadIdx.x, w = tid >> 6, l = tid & 63;
    const float* ib = in + (size_t)b * H * W * 256;

    int RT    = (SW == 64) ? w : (w & 1);        // 16-pixel row tile
    int ctoff = (SW == 64) ? 0 : ((w >> 1) * 2); // co-subtile base within 64-chunk
    int kA = (l >> 4) * 8;

    f32x4 acc[4 * NCT];
    #pragma unroll
    for (int i = 0; i < 4 * NCT; ++i) acc[i] = (f32x4){0.f, 0.f, 0.f, 0.f};

    // prefetch weight chunk 0
    short8 R[8];
    {
        const short8* p = (const short8*)wb;
        #pragma unroll
        for (int i = 0; i < 8; ++i) R[i] = p[tid + i * 256];
    }
    int c = 0;

    for (int ky = 0; ky < 3; ++ky) {
        int gy = y + ky - 1;
        __syncthreads();
        // stage input row (f32 -> bf16, swizzled)
        for (int t = tid; t < CX * 32; t += 256) {
            int cx = t >> 5;
            int e8 = (t & 31) * 8;
            int gx = x0 + cx - 1;
            float4 v0 = make_float4(0.f,0.f,0.f,0.f), v1 = v0;
            if (gy >= 0 && gy < H && gx >= 0 && gx < W) {
                v0 = *(const float4*)&ib[((size_t)gy * W + gx) * 256 + e8];
                v1 = *(const float4*)&ib[((size_t)gy * W + gx) * 256 + e8 + 4];
            }
            short8 p;
            p[0]=f2bf(v0.x); p[1]=f2bf(v0.y); p[2]=f2bf(v0.z); p[3]=f2bf(v0.w);
            p[4]=f2bf(v1.x); p[5]=f2bf(v1.y); p[6]=f2bf(v1.z); p[7]=f2bf(v1.w);
            *(short8*)&tile[cx * 256 + (e8 ^ ((cx & 15) << 3))] = p;
        }
        __syncthreads();
        for (int kx = 0; kx < 3; ++kx) {
            // A frags -> regs (reused across all 4 co-chunks)
            short8 af[8];
            int cx = RT * 16 + (l & 15) + kx;
            int swz = (cx & 15) << 3;
            #pragma unroll
            for (int ks = 0; ks < 8; ++ks)
                af[ks] = *(const short8*)&tile[cx * 256 + ((ks * 32 + kA) ^ swz)];
            for (int nc = 0; nc < 4; ++nc) {
                // write prefetched chunk -> LDS
                #pragma unroll
                for (int i = 0; i < 8; ++i) {
                    int g = tid + i * 256;
                    int n = g >> 5, e8 = (g & 31) * 8;
                    *(short8*)&wbuf[n * 256 + (e8 ^ ((n & 15) << 3))] = R[i];
                }
                // issue next chunk's loads (in flight across barrier + MFMA)
                ++c;
                if (c < 36) {
                    const short8* p = (const short8*)(wb + (size_t)c * 16384);
                    #pragma unroll
                    for (int i = 0; i < 8; ++i) R[i] = p[tid + i * 256];
                }
                __syncthreads();
                #pragma unroll
                for (int ks = 0; ks < 8; ++ks) {
                    #pragma unroll
                    for (int j = 0; j < NCT; ++j) {
                        int n = (ctoff + j) * 16 + (l & 15);
                        short8 bf = *(const short8*)&wbuf[n * 256 + ((ks * 32 + kA) ^ ((n & 15) << 3))];
                        acc[nc * NCT + j] = __builtin_amdgcn_mfma_f32_16x16x32_bf16(af[ks], bf, acc[nc * NCT + j], 0, 0, 0);
                    }
                }
                __syncthreads();
            }
        }
    }
    size_t orow = ((size_t)b * H + y) * W;
    #pragma unroll
    for (int q = 0; q < 4; ++q) {
        int px = x0 + RT * 16 + (l >> 4) * 4 + q;
        #pragma unroll
        for (int nc = 0; nc < 4; ++nc) {
            #pragma unroll
            for (int j = 0; j < NCT; ++j) {
                int n = nc * 64 + (ctoff + j) * 16 + (l & 15);
                out[(orow + px) * 256 + n] = acc[nc * NCT + j][q] + bias[n];
            }
        }
    }
}

// =====================================================================
// fused residual + LN + star-MLP via MFMA, LDS-staged weights.
// W1 reg-prefetched; W2 rows padded to 72 shorts (bank-phase spread).
// =====================================================================
__global__ __launch_bounds__(256)
void k_mlp_mfma(const float* __restrict__ a, const float* __restrict__ bsrc,
                const float* __restrict__ n2,
                const unsigned short* __restrict__ W1b, const unsigned short* __restrict__ W2b,
                const float* __restrict__ ssp, const float* __restrict__ sbp,
                float* __restrict__ out, int M) {
    __shared__ unsigned short buf[34816];  // Xn/W1c (16384) + W2c padded (256*72=18432)
    __shared__ unsigned short Hc[4096];    // per-wave 16x64 H slice
    int r0 = blockIdx.x * 64;
    int tid = threadIdx.x;
    int w = tid >> 6;
    int l = tid & 63;
    float ss = ssp[0], sb = sbp[0];

    // prefetch W1 chunk 0
    short8 R1[8];
    {
        const short8* p = (const short8*)W1b;
        #pragma unroll
        for (int i = 0; i < 8; ++i) R1[i] = p[tid + i * 256];
    }

    #pragma unroll 4
    for (int i = 0; i < 16; ++i) {
        int r = w * 16 + i;
        int row = r0 + r;
        float4 xa = make_float4(0.f,0.f,0.f,0.f), xb = xa;
        if (row < M) {
            xa = *(const float4*)&a[(size_t)row * 256 + l * 4];
            xb = *(const float4*)&bsrc[(size_t)row * 256 + l * 4];
        }
        float v0 = xa.x + xb.x, v1 = xa.y + xb.y, v2 = xa.z + xb.z, v3 = xa.w + xb.w;
        float s = v0 + v1 + v2 + v3;
        #pragma unroll
        for (int o = 32; o > 0; o >>= 1) s += __shfl_xor(s, o);
        float mean = s * (1.f / 256.f);
        float d0 = v0 - mean, d1 = v1 - mean, d2 = v2 - mean, d3 = v3 - mean;
        float vv = d0 * d0 + d1 * d1 + d2 * d2 + d3 * d3;
        #pragma unroll
        for (int o = 32; o > 0; o >>= 1) vv += __shfl_xor(vv, o);
        float rs = rsqrtf(vv * (1.f / 256.f) + EPS_);
        float4 nw = *(const float4*)&n2[l * 4];
        ushort4_ p;
        p.x = f2bf(d0 * rs * nw.x); p.y = f2bf(d1 * rs * nw.y);
        p.z = f2bf(d2 * rs * nw.z); p.w = f2bf(d3 * rs * nw.w);
        *(ushort4_*)&buf[r * 256 + ((l * 4) ^ ((r & 15) << 3))] = p;
    }
    __syncthreads();
    int rA = 16 * w + (l & 15);
    int kA = (l >> 4) * 8;
    int swzA = (rA & 15) << 3;
    short8 af[8];
    #pragma unroll
    for (int ks = 0; ks < 8; ++ks)
        af[ks] = *(const short8*)&buf[rA * 256 + ((kA + ks * 32) ^ swzA)];
    __syncthreads();

    f32x4 oacc[16];
    #pragma unroll
    for (int i = 0; i < 16; ++i) oacc[i] = (f32x4){0.f,0.f,0.f,0.f};

    for (int nc = 0; nc < 16; ++nc) {
        // write prefetched W1 chunk
        #pragma unroll
        for (int i = 0; i < 8; ++i) {
            int g = tid + i * 256;
            int n = g >> 5, e8 = (g & 31) * 8;
            *(short8*)&buf[n * 256 + (e8 ^ ((n & 15) << 3))] = R1[i];
        }
        if (nc + 1 < 16) {
            const short8* p = (const short8*)(W1b + (size_t)(nc + 1) * 16384);
            #pragma unroll
            for (int i = 0; i < 8; ++i) R1[i] = p[tid + i * 256];
        }
        // stage W2 chunk [256 o x 64 k] -> padded rows of 72
        for (int g = tid; g < 2048; g += 256) {
            int o = g >> 3, kb = g & 7;
            short8 p = *(const short8*)&W2b[(size_t)o * 1024 + nc * 64 + kb * 8];
            *(short8*)&buf[16384 + o * 72 + ((kb * 8) ^ ((o & 7) << 3))] = p;
        }
        __syncthreads();
        f32x4 hacc[4];
        #pragma unroll
        for (int i = 0; i < 4; ++i) hacc[i] = (f32x4){0.f,0.f,0.f,0.f};
        #pragma unroll
        for (int ks = 0; ks < 8; ++ks) {
            #pragma unroll
            for (int ct = 0; ct < 4; ++ct) {
                int n = ct * 16 + (l & 15);
                short8 bf = *(const short8*)&buf[n * 256 + ((kA + ks * 32) ^ ((n & 15) << 3))];
                hacc[ct] = __builtin_amdgcn_mfma_f32_16x16x32_bf16(af[ks], bf, hacc[ct], 0, 0, 0);
            }
        }
        #pragma unroll
        for (int ct = 0; ct < 4; ++ct) {
            #pragma unroll
            for (int q = 0; q < 4; ++q) {
                float hv = fmaxf(hacc[ct][q], 0.f);
                hv = ss * hv * hv + sb;
                int rr = (l >> 4) * 4 + q;
                int cc = ct * 16 + (l & 15);
                Hc[w * 1024 + rr * 64 + (cc ^ ((rr & 7) << 3))] = f2bf(hv);
            }
        }
        #pragma unroll
        for (int ks2 = 0; ks2 < 2; ++ks2) {
            short8 af2 = *(const short8*)&Hc[w * 1024 + (l & 15) * 64 + ((kA + ks2 * 32) ^ (((l & 15) & 7) << 3))];
            #pragma unroll
            for (int ot = 0; ot < 16; ++ot) {
                int o = ot * 16 + (l & 15);
                short8 bf2 = *(const short8*)&buf[16384 + o * 72 + ((kA + ks2 * 32) ^ ((o & 7) << 3))];
                oacc[ot] = __builtin_amdgcn_mfma_f32_16x16x32_bf16(af2, bf2, oacc[ot], 0, 0, 0);
            }
        }
        __syncthreads();
    }
    #pragma unroll
    for (int q = 0; q < 4; ++q) {
        int row = r0 + 16 * w + (l >> 4) * 4 + q;
        if (row < M) {
            #pragma unroll
            for (int ot = 0; ot < 16; ++ot) {
                int col = ot * 16 + (l & 15);
                size_t off = (size_t)row * 256 + col;
                out[off] = a[off] + bsrc[off] + oacc[ot][q];
            }
        }
    }
}

// ---------------- launch ----------------
extern "C" void kernel_launch(void* const* d_in, const int* in_sizes, int n_in,
                              void* d_out, int out_size, void* d_ws, size_t ws_size,
                              hipStream_t stream) {
    const float* src   = (const float*)d_in[0];
    const float* pos   = (const float*)d_in[1];
    const float* fpn   = (const float*)d_in[2];
    const float* refp  = (const float*)d_in[3];
    const float* n1w   = (const float*)d_in[5];
    const float* n2w   = (const float*)d_in[6];
    const float* Wv    = (const float*)d_in[7];
    const float* bv    = (const float*)d_in[8];
    const float* Woff  = (const float*)d_in[9];
    const float* boff  = (const float*)d_in[10];
    const float* Wattn = (const float*)d_in[11];
    const float* battn = (const float*)d_in[12];
    const float* Wout  = (const float*)d_in[13];
    const float* bout  = (const float*)d_in[14];
    const float* convw = (const float*)d_in[15];
    const float* convb = (const float*)d_in[16];
    const float* fc1   = (const float*)d_in[17];
    const float* fc2   = (const float*)d_in[18];
    const float* ssp   = (const float*)d_in[19];
    const float* sbp   = (const float*)d_in[20];

    float* ws = (float*)d_ws;
    float* S2 = ws + OFF_S2;
    float* QB = ws + OFF_QB;
    float* VB = ws + OFF_VB;
    float* OB = ws + OFF_OB;
    float* AW = ws + OFF_AW;
    float* CA = ws + OFF_CA;
    float* CB = ws + OFF_CB;
    unsigned short* W1B = (unsigned short*)(ws + OFF_W1B);
    unsigned short* W2B = (unsigned short*)(ws + OFF_W2B);
    unsigned short* CWB = (unsigned short*)(ws + OFF_CWB);
    unsigned short* WVB = (unsigned short*)(ws + OFF_WVB);
    unsigned short* WOFB = (unsigned short*)(ws + OFF_WOFB);
    unsigned short* WATB = (unsigned short*)(ws + OFF_WATB);
    unsigned short* WOUB = (unsigned short*)(ws + OFF_WOUB);
    float* out = (float*)d_out;

    // 0. weight prep (bf16)
    k_cvt_pad<<<1024, 256, 0, stream>>>(fc1, W1B, 262144, 262144);
    k_cvt_pad<<<1024, 256, 0, stream>>>(fc2, W2B, 262144, 262144);
    k_conv_w_prep<<<(1769472 + 255) / 256, 256, 0, stream>>>(convw, CWB);
    k_cvt_pad<<<256, 256, 0, stream>>>(Wv, WVB, 65536, 65536);
    k_cvt_pad<<<192, 256, 0, stream>>>(Woff, WOFB, 49152, 49152);
    k_cvt_pad<<<128, 256, 0, stream>>>(Wattn, WATB, 24576, 32768);
    k_cvt_pad<<<256, 256, 0, stream>>>(Wout, WOUB, 65536, 65536);

    // 1. LN(src) -> S2 ; query -> QB
    k_ln_src<<<B_ * LQ_, 256, 0, stream>>>(src, pos, n1w, S2, QB);

    // 2. value projection
    k_gemm_mfma<4><<<dim3(SUMHW_ / 64, B_), 256, 0, stream>>>(
        S2 + (size_t)RTOK * D_, (long long)LQ_ * D_, WVB, bv,
        VB, (long long)SUMHW_ * D_, SUMHW_, 256);

    // 3. offsets / attention logits
    k_gemm_mfma<3><<<dim3((B_ * LQ_ + 63) / 64, 1), 256, 0, stream>>>(
        QB, 0, WOFB, boff, OB, 0, B_ * LQ_, 192);
    k_gemm_mfma<2><<<dim3((B_ * LQ_ + 63) / 64, 1), 256, 0, stream>>>(
        QB, 0, WATB, battn, AW, 0, B_ * LQ_, 96);
    k_softmax12<<<(B_ * LQ_ * NH_ + 255) / 256, 256, 0, stream>>>(AW, B_ * LQ_ * NH_);

    // 4. deformable sampling -> AT (reuse QB)
    k_sample<<<B_ * LQ_, 256, 0, stream>>>(VB, OB, AW, refp, QB);

    // 5. src2 = AT @ Wout^T + bout -> S2
    k_gemm_mfma<4><<<dim3((B_ * LQ_ + 63) / 64, 1), 256, 0, stream>>>(
        QB, 0, WOUB, bout, S2, 0, B_ * LQ_, 256);

    // 6. FPN fusion chain (convs via MFMA, pipelined LDS-staged weights)
    k_build_f<<<B_ * 32 * 32, 256, 0, stream>>>(
        S2 + (size_t)(RTOK + 4096) * D_, (long long)LQ_ * D_, 0, n1w,
        S2 + (size_t)(RTOK + 5120) * D_, (long long)LQ_ * D_, 16, 16,
        CA, 32, 32);
    k_conv_mfma<32><<<32 * B_, 256, 0, stream>>>(CA, CWB, convb, CB, 32, 32);
    k_build_f<<<B_ * 64 * 64, 256, 0, stream>>>(
        S2 + (size_t)RTOK * D_, (long long)LQ_ * D_, 0, n1w,
        CB, (long long)32 * 32 * D_, 32, 32,
        CA, 64, 64);
    k_conv_mfma<64><<<64 * B_, 256, 0, stream>>>(CA, CWB + (size_t)9 * 65536, convb + D_, CB, 64, 64);
    k_build_f<<<B_ * 128 * 128, 256, 0, stream>>>(
        fpn, (long long)FH_ * FH_ * D_, 1, n1w,
        CB, (long long)64 * 64 * D_, 64, 64,
        CA, 128, 128);
    k_conv_mfma<64><<<2 * 128 * B_, 256, 0, stream>>>(CA, CWB + (size_t)18 * 65536, convb + 2 * D_, CB, 128, 128);

    // 7. fused residual + LN + MLP epilogues
    k_mlp_mfma<<<(B_ * LQ_ + 63) / 64, 256, 0, stream>>>(src, S2, n2w, W1B, W2B, ssp, sbp,
                                                         out, B_ * LQ_);
    k_mlp_mfma<<<(B_ * FH_ * FH_) / 64, 256, 0, stream>>>(fpn, CB, n2w, W1B, W2B, ssp, sbp,
                                                          out + (size_t)B_ * LQ_ * D_, B_ * FH_ * FH_);
}